// Round 1
// baseline (1256.648 us; speedup 1.0000x reference)
//
#include <hip/hip_runtime.h>
#include <hip/hip_bf16.h>
#include <cstddef>

#define N_NODES 50000
#define N_EDGES_RAW 800000
#define E_TOT (N_EDGES_RAW + N_NODES) /* 850000 */
#define DIM 128
#define NEG_SLOPE 0.2f

// ---------- float-as-ordered-unsigned encoding for atomicMax on floats ----------
__device__ __forceinline__ unsigned enc_f(float f) {
  unsigned u = __float_as_uint(f);
  return (u & 0x80000000u) ? ~u : (u | 0x80000000u);
}
__device__ __forceinline__ float dec_f(unsigned e) {
  unsigned u = (e & 0x80000000u) ? (e & 0x7FFFFFFFu) : ~e;
  return __uint_as_float(u);
}

// ---------- edge fetch robust to int32 vs int64 storage of edge_index ----------
__device__ __forceinline__ void get_edge(const int* __restrict__ ei, int is64,
                                         int e, int& s, int& d) {
  if (e >= N_EDGES_RAW) { s = e - N_EDGES_RAW; d = s; return; }
  if (is64) {
    s = ei[2 * (size_t)e];
    d = ei[2 * ((size_t)N_EDGES_RAW + (size_t)e)];
  } else {
    s = ei[e];
    d = ei[N_EDGES_RAW + e];
  }
}

// Detect whether edge_index buffer is int64 (little-endian: odd int32 words are
// the high halves, all zero since values < 50000) or int32.
__global__ void detect_i64(const int* __restrict__ ei, int* __restrict__ flag) {
  int is64 = 1;
  for (int i = 0; i < 64; ++i)
    if (ei[2 * i + 1] != 0) { is64 = 0; break; }
  *flag = is64;
}

// ---------- GEMM: out[n,128] = in[n,128] @ w[128,128] ----------
__global__ __launch_bounds__(256) void gemm128(const float* __restrict__ in,
                                               const float* __restrict__ w,
                                               float* __restrict__ out) {
  __shared__ float xs[16][128];
  const int t = threadIdx.x;
  const int r0 = blockIdx.x * 16;
#pragma unroll
  for (int i = 0; i < 8; ++i) {
    int idx = i * 256 + t;
    int r = idx >> 7, c = idx & 127;
    xs[r][c] = in[(size_t)(r0 + r) * DIM + c];
  }
  __syncthreads();
  const int col = t & 127;
  const int rb = (t >> 7) * 8;
  float acc[8] = {0.f, 0.f, 0.f, 0.f, 0.f, 0.f, 0.f, 0.f};
  for (int k = 0; k < DIM; ++k) {
    float wv = w[k * DIM + col];
#pragma unroll
    for (int r = 0; r < 8; ++r) acc[r] += xs[rb + r][k] * wv;
  }
#pragma unroll
  for (int r = 0; r < 8; ++r)
    out[(size_t)(r0 + rb + r) * DIM + col] = acc[r];
}

// ---------- per-node attention scores: a_src[n,H], a_dst[n,H] ----------
template <int H, int C>  // H*C == 128
__global__ __launch_bounds__(256) void att_scores(const float* __restrict__ h,
                                                  const float* __restrict__ att_src,
                                                  const float* __restrict__ att_dst,
                                                  float* __restrict__ a_src,
                                                  float* __restrict__ a_dst) {
  const int wid = threadIdx.x >> 6;
  const int lane = threadIdx.x & 63;
  const int node = blockIdx.x * 4 + wid;
  if (node >= N_NODES) return;
  const float2 hv = ((const float2*)(h + (size_t)node * DIM))[lane];
  const float2 as = ((const float2*)att_src)[lane];
  const float2 ad = ((const float2*)att_dst)[lane];
  float ps = hv.x * as.x + hv.y * as.y;
  float pd = hv.x * ad.x + hv.y * ad.y;
  constexpr int LPH = C / 2;  // lanes per head
#pragma unroll
  for (int m = 1; m < LPH; m <<= 1) {
    ps += __shfl_xor(ps, m, 64);
    pd += __shfl_xor(pd, m, 64);
  }
  if ((lane & (LPH - 1)) == 0) {
    int head = lane / LPH;
    a_src[(size_t)node * H + head] = ps;
    a_dst[(size_t)node * H + head] = pd;
  }
}

// ---------- edge pass 1: score + segment max (also stash raw score) ----------
template <int H>
__global__ __launch_bounds__(256) void edge_max(const int* __restrict__ ei,
                                                const int* __restrict__ flag,
                                                const float* __restrict__ a_src,
                                                const float* __restrict__ a_dst,
                                                unsigned* __restrict__ emax,
                                                float* __restrict__ alpha) {
  const int e = blockIdx.x * 256 + threadIdx.x;
  if (e >= E_TOT) return;
  int s, d;
  get_edge(ei, *flag, e, s, d);
#pragma unroll
  for (int h = 0; h < H; ++h) {
    float v = a_src[(size_t)s * H + h] + a_dst[(size_t)d * H + h];
    v = v > 0.f ? v : NEG_SLOPE * v;
    alpha[(size_t)e * H + h] = v;
    atomicMax(&emax[(size_t)d * H + h], enc_f(v));
  }
}

// ---------- edge pass 2: exp(v - max), denominator ----------
template <int H>
__global__ __launch_bounds__(256) void edge_exp(const int* __restrict__ ei,
                                                const int* __restrict__ flag,
                                                const unsigned* __restrict__ emax,
                                                float* __restrict__ alpha,
                                                float* __restrict__ denom) {
  const int e = blockIdx.x * 256 + threadIdx.x;
  if (e >= E_TOT) return;
  int s, d;
  get_edge(ei, *flag, e, s, d);
#pragma unroll
  for (int h = 0; h < H; ++h) {
    float v = alpha[(size_t)e * H + h];
    float m = dec_f(emax[(size_t)d * H + h]);
    float ex = expf(v - m);
    alpha[(size_t)e * H + h] = ex;
    atomicAdd(&denom[(size_t)d * H + h], ex);
  }
}

// ---------- edge pass 3: out[dst] += h[src] * alpha  (128 thr / edge) ----------
template <int H>
__global__ __launch_bounds__(256) void edge_agg(const int* __restrict__ ei,
                                                const int* __restrict__ flag,
                                                const float* __restrict__ hfeat,
                                                const float* __restrict__ alpha,
                                                const float* __restrict__ denom,
                                                float* __restrict__ out) {
  constexpr int C = DIM / H;
  const long long idx = (long long)blockIdx.x * 256 + threadIdx.x;
  const int e = (int)(idx >> 7);
  const int q = (int)(idx & 127);
  if (e >= E_TOT) return;
  int s, d;
  get_edge(ei, *flag, e, s, d);
  const int h = q / C;
  float a = alpha[(size_t)e * H + h] / (denom[(size_t)d * H + h] + 1e-16f);
  atomicAdd(&out[(size_t)d * DIM + q], hfeat[(size_t)s * DIM + q] * a);
}

// ---------- finalize: io = relu(io + bias) ----------
__global__ __launch_bounds__(256) void bias_relu(float* __restrict__ io,
                                                 const float* __restrict__ b) {
  size_t i = (size_t)blockIdx.x * 256 + threadIdx.x;
  io[i] = fmaxf(io[i] + b[i & 127], 0.f);
}

extern "C" void kernel_launch(void* const* d_in, const int* in_sizes, int n_in,
                              void* d_out, int out_size, void* d_ws, size_t ws_size,
                              hipStream_t stream) {
  const float* x   = (const float*)d_in[0];
  const int*   ei  = (const int*)d_in[1];
  const float* W1  = (const float*)d_in[2];
  const float* as1 = (const float*)d_in[3];
  const float* ad1 = (const float*)d_in[4];
  const float* b1  = (const float*)d_in[5];
  const float* W2  = (const float*)d_in[6];
  const float* as2 = (const float*)d_in[7];
  const float* ad2 = (const float*)d_in[8];
  const float* b2  = (const float*)d_in[9];
  float* out = (float*)d_out;

  float* ws = (float*)d_ws;
  const size_t F_H = (size_t)N_NODES * DIM;  // 6.4M
  float*    h     = ws;                       // 6.4M (reused as h2)
  float*    z     = ws + F_H;                 // 6.4M
  float*    alpha = ws + 2 * F_H;             // 3.4M (850000*4)
  float*    a_src = ws + 2 * F_H + 3400000;   // 200K
  float*    a_dst = a_src + 200000;           // 200K
  unsigned* emax  = (unsigned*)(a_dst + 200000);  // 200K
  float*    denom = (float*)(emax + 200000);      // 200K
  int*      flag  = (int*)(denom + 200000);       // 1

  const int EB = (E_TOT + 255) / 256;  // 3321

  hipLaunchKernelGGL(detect_i64, dim3(1), dim3(1), 0, stream, ei, flag);

  // ================= layer 1: GATConv(128 -> 32, heads=4) =================
  hipMemsetAsync(z, 0, F_H * sizeof(float), stream);
  hipMemsetAsync(emax, 0, 400000 * sizeof(float), stream);  // emax + denom

  hipLaunchKernelGGL(gemm128, dim3(N_NODES / 16), dim3(256), 0, stream, x, W1, h);
  hipLaunchKernelGGL((att_scores<4, 32>), dim3(N_NODES / 4), dim3(256), 0, stream,
                     h, as1, ad1, a_src, a_dst);
  hipLaunchKernelGGL((edge_max<4>), dim3(EB), dim3(256), 0, stream,
                     ei, flag, a_src, a_dst, emax, alpha);
  hipLaunchKernelGGL((edge_exp<4>), dim3(EB), dim3(256), 0, stream,
                     ei, flag, emax, alpha, denom);
  hipLaunchKernelGGL((edge_agg<4>), dim3(E_TOT / 2), dim3(256), 0, stream,
                     ei, flag, h, alpha, denom, z);
  hipLaunchKernelGGL(bias_relu, dim3(F_H / 256), dim3(256), 0, stream, z, b1);

  // ================= layer 2: GATConv(128 -> 128, heads=1) =================
  hipMemsetAsync(out, 0, F_H * sizeof(float), stream);
  hipMemsetAsync(emax, 0, 400000 * sizeof(float), stream);

  hipLaunchKernelGGL(gemm128, dim3(N_NODES / 16), dim3(256), 0, stream, z, W2, h);
  hipLaunchKernelGGL((att_scores<1, 128>), dim3(N_NODES / 4), dim3(256), 0, stream,
                     h, as2, ad2, a_src, a_dst);
  hipLaunchKernelGGL((edge_max<1>), dim3(EB), dim3(256), 0, stream,
                     ei, flag, a_src, a_dst, emax, alpha);
  hipLaunchKernelGGL((edge_exp<1>), dim3(EB), dim3(256), 0, stream,
                     ei, flag, emax, alpha, denom);
  hipLaunchKernelGGL((edge_agg<1>), dim3(E_TOT / 2), dim3(256), 0, stream,
                     ei, flag, h, alpha, denom, out);
  hipLaunchKernelGGL(bias_relu, dim3(F_H / 256), dim3(256), 0, stream, out, b2);
}

// Round 2
// 449.720 us; speedup vs baseline: 2.7943x; 2.7943x over previous
//
#include <hip/hip_runtime.h>
#include <hip/hip_bf16.h>
#include <cstddef>

#define N_NODES 50000
#define N_EDGES_RAW 800000
#define E_TOT (N_EDGES_RAW + N_NODES) /* 850000 */
#define DIM 128
#define NEG_SLOPE 0.2f

// ---------- edge fetch robust to int32 vs int64 storage of edge_index ----------
__device__ __forceinline__ void get_edge(const int* __restrict__ ei, int is64,
                                         int e, int& s, int& d) {
  if (e >= N_EDGES_RAW) { s = e - N_EDGES_RAW; d = s; return; }
  if (is64) {
    s = ei[2 * (size_t)e];
    d = ei[2 * ((size_t)N_EDGES_RAW + (size_t)e)];
  } else {
    s = ei[e];
    d = ei[N_EDGES_RAW + e];
  }
}

__global__ void detect_i64(const int* __restrict__ ei, int* __restrict__ flag) {
  int is64 = 1;
  for (int i = 0; i < 64; ++i)
    if (ei[2 * i + 1] != 0) { is64 = 0; break; }
  *flag = is64;
}

// ---------- CSR build ----------
__global__ __launch_bounds__(256) void count_deg(const int* __restrict__ ei,
                                                 const int* __restrict__ flag,
                                                 int* __restrict__ deg) {
  const int e = blockIdx.x * 256 + threadIdx.x;
  if (e >= E_TOT) return;
  int s, d;
  get_edge(ei, *flag, e, s, d);
  atomicAdd(&deg[d], 1);
}

// per-block (1024 elems) exclusive scan; block totals to bsum
__global__ __launch_bounds__(256) void scan_a(const int* __restrict__ deg,
                                              int* __restrict__ exc,
                                              int* __restrict__ bsum) {
  __shared__ int wsum[4];
  const int t = threadIdx.x;
  const int base = blockIdx.x * 1024 + t * 4;
  int v[4];
  int s = 0;
#pragma unroll
  for (int i = 0; i < 4; ++i) {
    v[i] = (base + i < N_NODES) ? deg[base + i] : 0;
    s += v[i];
  }
  const int lane = t & 63, wid = t >> 6;
  int sc = s;
#pragma unroll
  for (int m = 1; m < 64; m <<= 1) {
    int o = __shfl_up(sc, m, 64);
    if (lane >= m) sc += o;
  }
  if (lane == 63) wsum[wid] = sc;
  __syncthreads();
  int woff = 0;
  for (int w = 0; w < wid; ++w) woff += wsum[w];
  int run = woff + sc - s;  // exclusive prefix for this thread
#pragma unroll
  for (int i = 0; i < 4; ++i) {
    if (base + i < N_NODES) exc[base + i] = run;
    run += v[i];
  }
  if (t == 255) bsum[blockIdx.x] = woff + sc;
}

// single-wave exclusive scan of 49 block sums
__global__ __launch_bounds__(64) void scan_b(int* __restrict__ bsum, int nb) {
  const int lane = threadIdx.x;
  int v = (lane < nb) ? bsum[lane] : 0;
  int sc = v;
#pragma unroll
  for (int m = 1; m < 64; m <<= 1) {
    int o = __shfl_up(sc, m, 64);
    if (lane >= m) sc += o;
  }
  if (lane < nb) bsum[lane] = sc - v;
}

__global__ __launch_bounds__(256) void scan_c(const int* __restrict__ exc,
                                              const int* __restrict__ bsum,
                                              int* __restrict__ rp,
                                              int* __restrict__ cursor) {
  const int i = blockIdx.x * 256 + threadIdx.x;
  if (i >= N_NODES) return;
  int r = exc[i] + bsum[i >> 10];
  rp[i] = r;
  cursor[i] = r;
}

__global__ __launch_bounds__(256) void scatter(const int* __restrict__ ei,
                                               const int* __restrict__ flag,
                                               int* __restrict__ cursor,
                                               int* __restrict__ csr_src) {
  const int e = blockIdx.x * 256 + threadIdx.x;
  if (e >= E_TOT) return;
  int s, d;
  get_edge(ei, *flag, e, s, d);
  int pos = atomicAdd(&cursor[d], 1);
  csr_src[pos] = s;
}

// ---------- GEMM: out[n,128] = in[n,128] @ w[128,128] ----------
__global__ __launch_bounds__(256) void gemm128(const float* __restrict__ in,
                                               const float* __restrict__ w,
                                               float* __restrict__ out) {
  __shared__ float xs[16][128];
  const int t = threadIdx.x;
  const int r0 = blockIdx.x * 16;
#pragma unroll
  for (int i = 0; i < 8; ++i) {
    int idx = i * 256 + t;
    int r = idx >> 7, c = idx & 127;
    xs[r][c] = in[(size_t)(r0 + r) * DIM + c];
  }
  __syncthreads();
  const int col = t & 127;
  const int rb = (t >> 7) * 8;
  float acc[8] = {0.f, 0.f, 0.f, 0.f, 0.f, 0.f, 0.f, 0.f};
  for (int k = 0; k < DIM; k += 4) {
    float w0 = w[(k + 0) * DIM + col];
    float w1 = w[(k + 1) * DIM + col];
    float w2 = w[(k + 2) * DIM + col];
    float w3 = w[(k + 3) * DIM + col];
#pragma unroll
    for (int r = 0; r < 8; ++r) {
      float4 xv = *(const float4*)&xs[rb + r][k];
      acc[r] += xv.x * w0 + xv.y * w1 + xv.z * w2 + xv.w * w3;
    }
  }
#pragma unroll
  for (int r = 0; r < 8; ++r)
    out[(size_t)(r0 + rb + r) * DIM + col] = acc[r];
}

// ---------- per-node attention scores ----------
template <int H, int C>  // H*C == 128
__global__ __launch_bounds__(256) void att_scores(const float* __restrict__ h,
                                                  const float* __restrict__ att_src,
                                                  const float* __restrict__ att_dst,
                                                  float* __restrict__ a_src,
                                                  float* __restrict__ a_dst) {
  const int wid = threadIdx.x >> 6;
  const int lane = threadIdx.x & 63;
  const int node = blockIdx.x * 4 + wid;
  if (node >= N_NODES) return;
  const float2 hv = ((const float2*)(h + (size_t)node * DIM))[lane];
  const float2 as = ((const float2*)att_src)[lane];
  const float2 ad = ((const float2*)att_dst)[lane];
  float ps = hv.x * as.x + hv.y * as.y;
  float pd = hv.x * ad.x + hv.y * ad.y;
  constexpr int LPH = C / 2;
#pragma unroll
  for (int m = 1; m < LPH; m <<= 1) {
    ps += __shfl_xor(ps, m, 64);
    pd += __shfl_xor(pd, m, 64);
  }
  if ((lane & (LPH - 1)) == 0) {
    int head = lane / LPH;
    a_src[(size_t)node * H + head] = ps;
    a_dst[(size_t)node * H + head] = pd;
  }
}

// ---------- fused per-node softmax + aggregation + bias + relu ----------
// one wave per node; lane holds features (2*lane, 2*lane+1)
template <int H>
__global__ __launch_bounds__(256) void node_agg(const int* __restrict__ rp,
                                                const int* __restrict__ deg,
                                                const int* __restrict__ csr_src,
                                                const float* __restrict__ h,
                                                const float* __restrict__ a_src,
                                                const float* __restrict__ a_dst,
                                                const float* __restrict__ bias,
                                                float* __restrict__ outp) {
  const int wid = threadIdx.x >> 6;
  const int lane = threadIdx.x & 63;
  const int node = blockIdx.x * 4 + wid;
  if (node >= N_NODES) return;
  constexpr int LPH = (DIM / H) / 2;  // lanes per head
  const int head = lane / LPH;
  const float ad = a_dst[(size_t)node * H + head];
  const int beg = rp[node];
  const int dg = deg[node];
  const int* __restrict__ srcs = csr_src + beg;

  // pass 1: running max + denom (scalar online)
  float m = -3.4e38f, sden = 0.f;
  for (int j = 0; j < dg; ++j) {
    int s = srcs[j];
    float v = a_src[(size_t)s * H + head] + ad;
    v = v > 0.f ? v : NEG_SLOPE * v;
    if (v > m) {
      sden *= __expf(m - v);
      m = v;
    }
    sden += __expf(v - m);
  }
  const float inv = 1.f / (sden + 1e-16f);

  // pass 2: weighted gather-accumulate (no loop-carried dep except fp adds)
  float ax = 0.f, ay = 0.f;
#pragma unroll 4
  for (int j = 0; j < dg; ++j) {
    int s = srcs[j];
    float v = a_src[(size_t)s * H + head] + ad;
    v = v > 0.f ? v : NEG_SLOPE * v;
    float p = __expf(v - m);
    float2 hv = ((const float2*)(h + (size_t)s * DIM))[lane];
    ax += p * hv.x;
    ay += p * hv.y;
  }
  float2 bv = ((const float2*)bias)[lane];
  float ox = fmaxf(ax * inv + bv.x, 0.f);
  float oy = fmaxf(ay * inv + bv.y, 0.f);
  ((float2*)(outp + (size_t)node * DIM))[lane] = make_float2(ox, oy);
}

extern "C" void kernel_launch(void* const* d_in, const int* in_sizes, int n_in,
                              void* d_out, int out_size, void* d_ws, size_t ws_size,
                              hipStream_t stream) {
  const float* x   = (const float*)d_in[0];
  const int*   ei  = (const int*)d_in[1];
  const float* W1  = (const float*)d_in[2];
  const float* as1 = (const float*)d_in[3];
  const float* ad1 = (const float*)d_in[4];
  const float* b1  = (const float*)d_in[5];
  const float* W2  = (const float*)d_in[6];
  const float* as2 = (const float*)d_in[7];
  const float* ad2 = (const float*)d_in[8];
  const float* b2  = (const float*)d_in[9];
  float* out = (float*)d_out;

  float* ws = (float*)d_ws;
  const size_t F_H = (size_t)N_NODES * DIM;  // 6.4M
  float* h       = ws;                   // 6,400,000
  float* z       = h + F_H;              // 6,400,000
  float* a_src   = z + F_H;              // 200,000
  float* a_dst   = a_src + 200000;       // 200,000
  int*   deg     = (int*)(a_dst + 200000);  // 50,000
  int*   exc     = deg + N_NODES;        // 50,176
  int*   bsum    = exc + 50176;          // 64
  int*   rp      = bsum + 64;            // 50,000
  int*   cursor  = rp + N_NODES;         // 50,000
  int*   csr_src = cursor + N_NODES;     // 850,000
  int*   flag    = csr_src + E_TOT;      // 1

  const int EB = (E_TOT + 255) / 256;          // 3321
  const int NB_SCAN = (N_NODES + 1023) / 1024; // 49

  // ---- CSR build (shared by both layers) ----
  hipLaunchKernelGGL(detect_i64, dim3(1), dim3(1), 0, stream, ei, flag);
  hipMemsetAsync(deg, 0, N_NODES * sizeof(int), stream);
  hipLaunchKernelGGL(count_deg, dim3(EB), dim3(256), 0, stream, ei, flag, deg);
  hipLaunchKernelGGL(scan_a, dim3(NB_SCAN), dim3(256), 0, stream, deg, exc, bsum);
  hipLaunchKernelGGL(scan_b, dim3(1), dim3(64), 0, stream, bsum, NB_SCAN);
  hipLaunchKernelGGL(scan_c, dim3((N_NODES + 255) / 256), dim3(256), 0, stream,
                     exc, bsum, rp, cursor);
  hipLaunchKernelGGL(scatter, dim3(EB), dim3(256), 0, stream, ei, flag, cursor, csr_src);

  // ---- layer 1: GATConv(128 -> 32, heads=4) ----
  hipLaunchKernelGGL(gemm128, dim3(N_NODES / 16), dim3(256), 0, stream, x, W1, h);
  hipLaunchKernelGGL((att_scores<4, 32>), dim3(N_NODES / 4), dim3(256), 0, stream,
                     h, as1, ad1, a_src, a_dst);
  hipLaunchKernelGGL((node_agg<4>), dim3((N_NODES + 3) / 4), dim3(256), 0, stream,
                     rp, deg, csr_src, h, a_src, a_dst, b1, z);

  // ---- layer 2: GATConv(128 -> 128, heads=1) ----
  hipLaunchKernelGGL(gemm128, dim3(N_NODES / 16), dim3(256), 0, stream, z, W2, h);
  hipLaunchKernelGGL((att_scores<1, 128>), dim3(N_NODES / 4), dim3(256), 0, stream,
                     h, as2, ad2, a_src, a_dst);
  hipLaunchKernelGGL((node_agg<1>), dim3((N_NODES + 3) / 4), dim3(256), 0, stream,
                     rp, deg, csr_src, h, a_src, a_dst, b2, out);
}

// Round 3
// 337.684 us; speedup vs baseline: 3.7214x; 1.3318x over previous
//
#include <hip/hip_runtime.h>
#include <hip/hip_bf16.h>
#include <cstddef>

#define N_NODES 50000
#define N_EDGES_RAW 800000
#define E_TOT (N_EDGES_RAW + N_NODES) /* 850000 */
#define DIM 128
#define NEG_SLOPE 0.2f

// ---------- edge fetch robust to int32 vs int64 storage of edge_index ----------
__device__ __forceinline__ void get_edge(const int* __restrict__ ei, int is64,
                                         int e, int& s, int& d) {
  if (e >= N_EDGES_RAW) { s = e - N_EDGES_RAW; d = s; return; }
  if (is64) {
    s = ei[2 * (size_t)e];
    d = ei[2 * ((size_t)N_EDGES_RAW + (size_t)e)];
  } else {
    s = ei[e];
    d = ei[N_EDGES_RAW + e];
  }
}

// one wave: lane i checks high word of element i; int64 iff all high words zero
__global__ void detect_i64(const int* __restrict__ ei, int* __restrict__ flag) {
  const int lane = threadIdx.x & 63;
  int hi = ei[2 * lane + 1];
  unsigned long long b = __ballot(hi != 0);
  if (lane == 0) *flag = (b == 0ULL) ? 1 : 0;
}

// ---------- CSR build ----------
__global__ __launch_bounds__(256) void count_deg(const int* __restrict__ ei,
                                                 const int* __restrict__ flag,
                                                 int* __restrict__ deg) {
  const int e = blockIdx.x * 256 + threadIdx.x;
  if (e >= E_TOT) return;
  int s, d;
  get_edge(ei, *flag, e, s, d);
  atomicAdd(&deg[d], 1);
}

// per-block (1024 elems) exclusive scan; block totals to bsum
__global__ __launch_bounds__(256) void scan_a(const int* __restrict__ deg,
                                              int* __restrict__ exc,
                                              int* __restrict__ bsum) {
  __shared__ int wsum[4];
  const int t = threadIdx.x;
  const int base = blockIdx.x * 1024 + t * 4;
  int v[4];
  int s = 0;
#pragma unroll
  for (int i = 0; i < 4; ++i) {
    v[i] = (base + i < N_NODES) ? deg[base + i] : 0;
    s += v[i];
  }
  const int lane = t & 63, wid = t >> 6;
  int sc = s;
#pragma unroll
  for (int m = 1; m < 64; m <<= 1) {
    int o = __shfl_up(sc, m, 64);
    if (lane >= m) sc += o;
  }
  if (lane == 63) wsum[wid] = sc;
  __syncthreads();
  int woff = 0;
  for (int w = 0; w < wid; ++w) woff += wsum[w];
  int run = woff + sc - s;  // exclusive prefix for this thread
#pragma unroll
  for (int i = 0; i < 4; ++i) {
    if (base + i < N_NODES) exc[base + i] = run;
    run += v[i];
  }
  if (t == 255) bsum[blockIdx.x] = woff + sc;
}

// single-wave exclusive scan of 49 block sums
__global__ __launch_bounds__(64) void scan_b(int* __restrict__ bsum, int nb) {
  const int lane = threadIdx.x;
  int v = (lane < nb) ? bsum[lane] : 0;
  int sc = v;
#pragma unroll
  for (int m = 1; m < 64; m <<= 1) {
    int o = __shfl_up(sc, m, 64);
    if (lane >= m) sc += o;
  }
  if (lane < nb) bsum[lane] = sc - v;
}

__global__ __launch_bounds__(256) void scan_c(const int* __restrict__ exc,
                                              const int* __restrict__ bsum,
                                              int* __restrict__ rp,
                                              int* __restrict__ cursor) {
  const int i = blockIdx.x * 256 + threadIdx.x;
  if (i >= N_NODES) return;
  int r = exc[i] + bsum[i >> 10];
  rp[i] = r;
  cursor[i] = r;
}

__global__ __launch_bounds__(256) void scatter(const int* __restrict__ ei,
                                               const int* __restrict__ flag,
                                               int* __restrict__ cursor,
                                               int* __restrict__ csr_src) {
  const int e = blockIdx.x * 256 + threadIdx.x;
  if (e >= E_TOT) return;
  int s, d;
  get_edge(ei, *flag, e, s, d);
  int pos = atomicAdd(&cursor[d], 1);
  csr_src[pos] = s;
}

// ---------- GEMM: out[n,128] = in[n,128] @ w[128,128] ----------
__global__ __launch_bounds__(256) void gemm128(const float* __restrict__ in,
                                               const float* __restrict__ w,
                                               float* __restrict__ out) {
  __shared__ float xs[16][128];
  const int t = threadIdx.x;
  const int r0 = blockIdx.x * 16;
#pragma unroll
  for (int i = 0; i < 8; ++i) {
    int idx = i * 256 + t;
    int r = idx >> 7, c = idx & 127;
    xs[r][c] = in[(size_t)(r0 + r) * DIM + c];
  }
  __syncthreads();
  const int col = t & 127;
  const int rb = (t >> 7) * 8;
  float acc[8] = {0.f, 0.f, 0.f, 0.f, 0.f, 0.f, 0.f, 0.f};
  for (int k = 0; k < DIM; k += 4) {
    float w0 = w[(k + 0) * DIM + col];
    float w1 = w[(k + 1) * DIM + col];
    float w2 = w[(k + 2) * DIM + col];
    float w3 = w[(k + 3) * DIM + col];
#pragma unroll
    for (int r = 0; r < 8; ++r) {
      float4 xv = *(const float4*)&xs[rb + r][k];
      acc[r] += xv.x * w0 + xv.y * w1 + xv.z * w2 + xv.w * w3;
    }
  }
#pragma unroll
  for (int r = 0; r < 8; ++r)
    out[(size_t)(r0 + rb + r) * DIM + col] = acc[r];
}

// ---------- per-node attention scores ----------
template <int H, int C>  // H*C == 128
__global__ __launch_bounds__(256) void att_scores(const float* __restrict__ h,
                                                  const float* __restrict__ att_src,
                                                  const float* __restrict__ att_dst,
                                                  float* __restrict__ a_src,
                                                  float* __restrict__ a_dst) {
  const int wid = threadIdx.x >> 6;
  const int lane = threadIdx.x & 63;
  const int node = blockIdx.x * 4 + wid;
  if (node >= N_NODES) return;
  const float2 hv = ((const float2*)(h + (size_t)node * DIM))[lane];
  const float2 as = ((const float2*)att_src)[lane];
  const float2 ad = ((const float2*)att_dst)[lane];
  float ps = hv.x * as.x + hv.y * as.y;
  float pd = hv.x * ad.x + hv.y * ad.y;
  constexpr int LPH = C / 2;
#pragma unroll
  for (int m = 1; m < LPH; m <<= 1) {
    ps += __shfl_xor(ps, m, 64);
    pd += __shfl_xor(pd, m, 64);
  }
  if ((lane & (LPH - 1)) == 0) {
    int head = lane / LPH;
    a_src[(size_t)node * H + head] = ps;
    a_dst[(size_t)node * H + head] = pd;
  }
}

// ---------- fused SINGLE-PASS softmax + aggregation + bias + relu ----------
// softmax is shift-invariant: sum(exp(v)*h)/sum(exp(v)) == reference.
// clamp v to [-60, 80] keeps exp() in normal f32 range (scores are O(+-10)).
template <int H>
__global__ __launch_bounds__(256) void node_agg(const int* __restrict__ rp,
                                                const int* __restrict__ deg,
                                                const int* __restrict__ csr_src,
                                                const float* __restrict__ h,
                                                const float* __restrict__ a_src,
                                                const float* __restrict__ a_dst,
                                                const float* __restrict__ bias,
                                                float* __restrict__ outp) {
  const int wid = threadIdx.x >> 6;
  const int lane = threadIdx.x & 63;
  const int node = blockIdx.x * 4 + wid;
  if (node >= N_NODES) return;
  constexpr int LPH = (DIM / H) / 2;  // lanes per head
  const int head = lane / LPH;
  const float ad = a_dst[(size_t)node * H + head];
  const int beg = rp[node];
  const int dg = deg[node];
  const int* __restrict__ srcs = csr_src + beg;

  float sden = 0.f, ax = 0.f, ay = 0.f;
#pragma unroll 4
  for (int j = 0; j < dg; ++j) {
    int s = srcs[j];
    float v = a_src[(size_t)s * H + head] + ad;
    v = v > 0.f ? v : NEG_SLOPE * v;
    v = fminf(fmaxf(v, -60.f), 80.f);
    float p = __expf(v);
    float2 hv = ((const float2*)(h + (size_t)s * DIM))[lane];
    sden += p;
    ax += p * hv.x;
    ay += p * hv.y;
  }
  const float inv = 1.f / sden;  // sden >= exp(-60) > 0 always
  float2 bv = ((const float2*)bias)[lane];
  float ox = fmaxf(ax * inv + bv.x, 0.f);
  float oy = fmaxf(ay * inv + bv.y, 0.f);
  ((float2*)(outp + (size_t)node * DIM))[lane] = make_float2(ox, oy);
}

extern "C" void kernel_launch(void* const* d_in, const int* in_sizes, int n_in,
                              void* d_out, int out_size, void* d_ws, size_t ws_size,
                              hipStream_t stream) {
  const float* x   = (const float*)d_in[0];
  const int*   ei  = (const int*)d_in[1];
  const float* W1  = (const float*)d_in[2];
  const float* as1 = (const float*)d_in[3];
  const float* ad1 = (const float*)d_in[4];
  const float* b1  = (const float*)d_in[5];
  const float* W2  = (const float*)d_in[6];
  const float* as2 = (const float*)d_in[7];
  const float* ad2 = (const float*)d_in[8];
  const float* b2  = (const float*)d_in[9];
  float* out = (float*)d_out;

  float* ws = (float*)d_ws;
  const size_t F_H = (size_t)N_NODES * DIM;  // 6.4M
  float* h       = ws;                   // 6,400,000
  float* z       = h + F_H;              // 6,400,000
  float* a_src   = z + F_H;              // 200,000
  float* a_dst   = a_src + 200000;       // 200,000
  int*   deg     = (int*)(a_dst + 200000);  // 50,000
  int*   exc     = deg + N_NODES;        // 50,176
  int*   bsum    = exc + 50176;          // 64
  int*   rp      = bsum + 64;            // 50,000
  int*   cursor  = rp + N_NODES;         // 50,000
  int*   csr_src = cursor + N_NODES;     // 850,000
  int*   flag    = csr_src + E_TOT;      // 1

  const int EB = (E_TOT + 255) / 256;          // 3321
  const int NB_SCAN = (N_NODES + 1023) / 1024; // 49

  // ---- CSR build (shared by both layers) ----
  hipLaunchKernelGGL(detect_i64, dim3(1), dim3(64), 0, stream, ei, flag);
  hipMemsetAsync(deg, 0, N_NODES * sizeof(int), stream);
  hipLaunchKernelGGL(count_deg, dim3(EB), dim3(256), 0, stream, ei, flag, deg);
  hipLaunchKernelGGL(scan_a, dim3(NB_SCAN), dim3(256), 0, stream, deg, exc, bsum);
  hipLaunchKernelGGL(scan_b, dim3(1), dim3(64), 0, stream, bsum, NB_SCAN);
  hipLaunchKernelGGL(scan_c, dim3((N_NODES + 255) / 256), dim3(256), 0, stream,
                     exc, bsum, rp, cursor);
  hipLaunchKernelGGL(scatter, dim3(EB), dim3(256), 0, stream, ei, flag, cursor, csr_src);

  // ---- layer 1: GATConv(128 -> 32, heads=4) ----
  hipLaunchKernelGGL(gemm128, dim3(N_NODES / 16), dim3(256), 0, stream, x, W1, h);
  hipLaunchKernelGGL((att_scores<4, 32>), dim3(N_NODES / 4), dim3(256), 0, stream,
                     h, as1, ad1, a_src, a_dst);
  hipLaunchKernelGGL((node_agg<4>), dim3((N_NODES + 3) / 4), dim3(256), 0, stream,
                     rp, deg, csr_src, h, a_src, a_dst, b1, z);

  // ---- layer 2: GATConv(128 -> 128, heads=1) ----
  hipLaunchKernelGGL(gemm128, dim3(N_NODES / 16), dim3(256), 0, stream, z, W2, h);
  hipLaunchKernelGGL((att_scores<1, 128>), dim3(N_NODES / 4), dim3(256), 0, stream,
                     h, as2, ad2, a_src, a_dst);
  hipLaunchKernelGGL((node_agg<1>), dim3((N_NODES + 3) / 4), dim3(256), 0, stream,
                     rp, deg, csr_src, h, a_src, a_dst, b2, out);
}

// Round 4
// 289.718 us; speedup vs baseline: 4.3375x; 1.1656x over previous
//
#include <hip/hip_runtime.h>
#include <hip/hip_bf16.h>
#include <cstddef>

#define N_NODES 50000
#define N_EDGES_RAW 800000
#define E_TOT (N_EDGES_RAW + N_NODES) /* 850000 */
#define DIM 128
#define NEG_SLOPE 0.2f

// ---------- edge fetch robust to int32 vs int64 storage of edge_index ----------
__device__ __forceinline__ void get_edge(const int* __restrict__ ei, int is64,
                                         int e, int& s, int& d) {
  if (e >= N_EDGES_RAW) { s = e - N_EDGES_RAW; d = s; return; }
  if (is64) {
    s = ei[2 * (size_t)e];
    d = ei[2 * ((size_t)N_EDGES_RAW + (size_t)e)];
  } else {
    s = ei[e];
    d = ei[N_EDGES_RAW + e];
  }
}

// one wave: lane i checks high word of element i; int64 iff all high words zero
__global__ void detect_i64(const int* __restrict__ ei, int* __restrict__ flag) {
  const int lane = threadIdx.x & 63;
  int hi = ei[2 * lane + 1];
  unsigned long long b = __ballot(hi != 0);
  if (lane == 0) *flag = (b == 0ULL) ? 1 : 0;
}

// ---------- CSR build ----------
__global__ __launch_bounds__(256) void count_deg(const int* __restrict__ ei,
                                                 const int* __restrict__ flag,
                                                 int* __restrict__ deg) {
  const int e = blockIdx.x * 256 + threadIdx.x;
  if (e >= E_TOT) return;
  int s, d;
  get_edge(ei, *flag, e, s, d);
  atomicAdd(&deg[d], 1);
}

__global__ __launch_bounds__(256) void scan_a(const int* __restrict__ deg,
                                              int* __restrict__ exc,
                                              int* __restrict__ bsum) {
  __shared__ int wsum[4];
  const int t = threadIdx.x;
  const int base = blockIdx.x * 1024 + t * 4;
  int v[4];
  int s = 0;
#pragma unroll
  for (int i = 0; i < 4; ++i) {
    v[i] = (base + i < N_NODES) ? deg[base + i] : 0;
    s += v[i];
  }
  const int lane = t & 63, wid = t >> 6;
  int sc = s;
#pragma unroll
  for (int m = 1; m < 64; m <<= 1) {
    int o = __shfl_up(sc, m, 64);
    if (lane >= m) sc += o;
  }
  if (lane == 63) wsum[wid] = sc;
  __syncthreads();
  int woff = 0;
  for (int w = 0; w < wid; ++w) woff += wsum[w];
  int run = woff + sc - s;
#pragma unroll
  for (int i = 0; i < 4; ++i) {
    if (base + i < N_NODES) exc[base + i] = run;
    run += v[i];
  }
  if (t == 255) bsum[blockIdx.x] = woff + sc;
}

__global__ __launch_bounds__(64) void scan_b(int* __restrict__ bsum, int nb) {
  const int lane = threadIdx.x;
  int v = (lane < nb) ? bsum[lane] : 0;
  int sc = v;
#pragma unroll
  for (int m = 1; m < 64; m <<= 1) {
    int o = __shfl_up(sc, m, 64);
    if (lane >= m) sc += o;
  }
  if (lane < nb) bsum[lane] = sc - v;
}

__global__ __launch_bounds__(256) void scan_c(const int* __restrict__ exc,
                                              const int* __restrict__ bsum,
                                              int* __restrict__ rp,
                                              int* __restrict__ cursor) {
  const int i = blockIdx.x * 256 + threadIdx.x;
  if (i >= N_NODES) return;
  int r = exc[i] + bsum[i >> 10];
  rp[i] = r;
  cursor[i] = r;
}

__global__ __launch_bounds__(256) void scatter(const int* __restrict__ ei,
                                               const int* __restrict__ flag,
                                               int* __restrict__ cursor,
                                               int* __restrict__ csr_src) {
  const int e = blockIdx.x * 256 + threadIdx.x;
  if (e >= E_TOT) return;
  int s, d;
  get_edge(ei, *flag, e, s, d);
  int pos = atomicAdd(&cursor[d], 1);
  csr_src[pos] = s;
}

// ---------- fused GEMM + attention scores + bf16 cast ----------
// out: h_bf[n,128] (bf16), a_src[n,H], a_dst[n,H]. No f32 h materialized.
// att vectors are flat[128]: att[h][c] == att_flat[h*C+c] == att_flat[col].
template <int H>
__global__ __launch_bounds__(256) void gemm_att(const float* __restrict__ in,
                                                const float* __restrict__ w,
                                                const float* __restrict__ atts,
                                                const float* __restrict__ attd,
                                                __hip_bfloat16* __restrict__ h_bf,
                                                float* __restrict__ a_src,
                                                float* __restrict__ a_dst) {
  __shared__ float xs[16][128];
  __shared__ float sAs[16][2], sAd[16][2];  // used only for H==1
  const int t = threadIdx.x;
  const int r0 = blockIdx.x * 16;
#pragma unroll
  for (int i = 0; i < 8; ++i) {
    int idx = i * 256 + t;
    int r = idx >> 7, c = idx & 127;
    xs[r][c] = in[(size_t)(r0 + r) * DIM + c];
  }
  __syncthreads();
  const int col = t & 127;
  const int rb = (t >> 7) * 8;
  float acc[8] = {0.f, 0.f, 0.f, 0.f, 0.f, 0.f, 0.f, 0.f};
  for (int k = 0; k < DIM; k += 4) {
    float w0 = w[(k + 0) * DIM + col];
    float w1 = w[(k + 1) * DIM + col];
    float w2 = w[(k + 2) * DIM + col];
    float w3 = w[(k + 3) * DIM + col];
#pragma unroll
    for (int r = 0; r < 8; ++r) {
      float4 xv = *(const float4*)&xs[rb + r][k];
      acc[r] += xv.x * w0 + xv.y * w1 + xv.z * w2 + xv.w * w3;
    }
  }
  // h (bf16) store
#pragma unroll
  for (int r = 0; r < 8; ++r)
    h_bf[(size_t)(r0 + rb + r) * DIM + col] = __float2bfloat16(acc[r]);

  // attention score reduction
  const float asv = atts[col];
  const float adv = attd[col];
  const int lane = t & 63;
#pragma unroll
  for (int r = 0; r < 8; ++r) {
    float ps = acc[r] * asv;
    float pd = acc[r] * adv;
    if (H == 4) {
      // 32-lane segment == one head (cols are contiguous per half-wave)
#pragma unroll
      for (int m = 1; m < 32; m <<= 1) {
        ps += __shfl_xor(ps, m, 64);
        pd += __shfl_xor(pd, m, 64);
      }
      if ((lane & 31) == 0) {
        int head = col >> 5;
        a_src[(size_t)(r0 + rb + r) * 4 + head] = ps;
        a_dst[(size_t)(r0 + rb + r) * 4 + head] = pd;
      }
    } else {
      // full-wave sum, then cross-wave combine via LDS
#pragma unroll
      for (int m = 1; m < 64; m <<= 1) {
        ps += __shfl_xor(ps, m, 64);
        pd += __shfl_xor(pd, m, 64);
      }
      if (lane == 0) {
        int half = (t >> 6) & 1;  // col >= 64 ?
        sAs[rb + r][half] = ps;
        sAd[rb + r][half] = pd;
      }
    }
  }
  if (H == 1) {
    __syncthreads();
    if (t < 16) {
      a_src[r0 + t] = sAs[t][0] + sAs[t][1];
    } else if (t < 32) {
      a_dst[r0 + t - 16] = sAd[t - 16][0] + sAd[t - 16][1];
    }
  }
}

// ---------- fused single-pass softmax + bf16 gather + bias + relu ----------
template <int H>
__global__ __launch_bounds__(256) void node_agg(const int* __restrict__ rp,
                                                const int* __restrict__ deg,
                                                const int* __restrict__ csr_src,
                                                const __hip_bfloat16* __restrict__ h_bf,
                                                const float* __restrict__ a_src,
                                                const float* __restrict__ a_dst,
                                                const float* __restrict__ bias,
                                                float* __restrict__ outp) {
  const int wid = threadIdx.x >> 6;
  const int lane = threadIdx.x & 63;
  const int node = blockIdx.x * 4 + wid;
  if (node >= N_NODES) return;
  constexpr int LPH = (DIM / H) / 2;  // lanes per head
  const int head = lane / LPH;
  const float ad = a_dst[(size_t)node * H + head];
  const int beg = rp[node];
  const int dg = deg[node];
  const int* __restrict__ srcs = csr_src + beg;

  float sden = 0.f, ax = 0.f, ay = 0.f;
#pragma unroll 4
  for (int j = 0; j < dg; ++j) {
    int s = srcs[j];
    float v = a_src[(size_t)s * H + head] + ad;
    v = v > 0.f ? v : NEG_SLOPE * v;
    v = fminf(fmaxf(v, -60.f), 80.f);
    float p = __expf(v);
    // 64 lanes x 4B = one 256B row of bf16 features
    ushort2 hv = ((const ushort2*)(h_bf + (size_t)s * DIM))[lane];
    float hx = __bfloat162float(*(const __hip_bfloat16*)&hv.x);
    float hy = __bfloat162float(*(const __hip_bfloat16*)&hv.y);
    sden += p;
    ax += p * hx;
    ay += p * hy;
  }
  const float inv = 1.f / sden;
  float2 bv = ((const float2*)bias)[lane];
  float ox = fmaxf(ax * inv + bv.x, 0.f);
  float oy = fmaxf(ay * inv + bv.y, 0.f);
  ((float2*)(outp + (size_t)node * DIM))[lane] = make_float2(ox, oy);
}

extern "C" void kernel_launch(void* const* d_in, const int* in_sizes, int n_in,
                              void* d_out, int out_size, void* d_ws, size_t ws_size,
                              hipStream_t stream) {
  const float* x   = (const float*)d_in[0];
  const int*   ei  = (const int*)d_in[1];
  const float* W1  = (const float*)d_in[2];
  const float* as1 = (const float*)d_in[3];
  const float* ad1 = (const float*)d_in[4];
  const float* b1  = (const float*)d_in[5];
  const float* W2  = (const float*)d_in[6];
  const float* as2 = (const float*)d_in[7];
  const float* ad2 = (const float*)d_in[8];
  const float* b2  = (const float*)d_in[9];
  float* out = (float*)d_out;

  float* ws = (float*)d_ws;
  const size_t F_H = (size_t)N_NODES * DIM;  // 6.4M elems
  float* z       = ws;                       // 6,400,000 f32
  __hip_bfloat16* h_bf = (__hip_bfloat16*)(z + F_H);  // 6.4M bf16 = 3.2M f32 slots
  float* a_src   = z + F_H + F_H / 2;        // 200,000
  float* a_dst   = a_src + 200000;           // 200,000
  int*   deg     = (int*)(a_dst + 200000);   // 50,000
  int*   exc     = deg + N_NODES;            // 50,176
  int*   bsum    = exc + 50176;              // 64
  int*   rp      = bsum + 64;                // 50,000
  int*   cursor  = rp + N_NODES;             // 50,000
  int*   csr_src = cursor + N_NODES;         // 850,000
  int*   flag    = csr_src + E_TOT;          // 1

  const int EB = (E_TOT + 255) / 256;          // 3321
  const int NB_SCAN = (N_NODES + 1023) / 1024; // 49

  // ---- CSR build (shared by both layers) ----
  hipLaunchKernelGGL(detect_i64, dim3(1), dim3(64), 0, stream, ei, flag);
  hipMemsetAsync(deg, 0, N_NODES * sizeof(int), stream);
  hipLaunchKernelGGL(count_deg, dim3(EB), dim3(256), 0, stream, ei, flag, deg);
  hipLaunchKernelGGL(scan_a, dim3(NB_SCAN), dim3(256), 0, stream, deg, exc, bsum);
  hipLaunchKernelGGL(scan_b, dim3(1), dim3(64), 0, stream, bsum, NB_SCAN);
  hipLaunchKernelGGL(scan_c, dim3((N_NODES + 255) / 256), dim3(256), 0, stream,
                     exc, bsum, rp, cursor);
  hipLaunchKernelGGL(scatter, dim3(EB), dim3(256), 0, stream, ei, flag, cursor, csr_src);

  // ---- layer 1: GATConv(128 -> 32, heads=4) ----
  hipLaunchKernelGGL((gemm_att<4>), dim3(N_NODES / 16), dim3(256), 0, stream,
                     x, W1, as1, ad1, h_bf, a_src, a_dst);
  hipLaunchKernelGGL((node_agg<4>), dim3((N_NODES + 3) / 4), dim3(256), 0, stream,
                     rp, deg, csr_src, h_bf, a_src, a_dst, b1, z);

  // ---- layer 2: GATConv(128 -> 128, heads=1) ----
  hipLaunchKernelGGL((gemm_att<1>), dim3(N_NODES / 16), dim3(256), 0, stream,
                     z, W2, as2, ad2, h_bf, a_src, a_dst);
  hipLaunchKernelGGL((node_agg<1>), dim3((N_NODES + 3) / 4), dim3(256), 0, stream,
                     rp, deg, csr_src, h_bf, a_src, a_dst, b2, out);
}

// Round 5
// 248.333 us; speedup vs baseline: 5.0603x; 1.1667x over previous
//
#include <hip/hip_runtime.h>
#include <hip/hip_bf16.h>
#include <cstddef>

#define N_NODES 50000
#define N_EDGES_RAW 800000
#define E_TOT (N_EDGES_RAW + N_NODES) /* 850000 */
#define DIM 128
#define NEG_SLOPE 0.2f

typedef __attribute__((ext_vector_type(8))) short bf16x8;
typedef __attribute__((ext_vector_type(4))) float f32x4;

// round-to-nearest-even f32 -> bf16 bits
__device__ __forceinline__ ushort f2bf(float f) {
  unsigned u = __float_as_uint(f);
  return (ushort)((u + 0x7FFFu + ((u >> 16) & 1u)) >> 16);
}

// ---------- edge fetch robust to int32 vs int64 storage of edge_index ----------
__device__ __forceinline__ void get_edge(const int* __restrict__ ei, int is64,
                                         int e, int& s, int& d) {
  if (e >= N_EDGES_RAW) { s = e - N_EDGES_RAW; d = s; return; }
  if (is64) {
    s = ei[2 * (size_t)e];
    d = ei[2 * ((size_t)N_EDGES_RAW + (size_t)e)];
  } else {
    s = ei[e];
    d = ei[N_EDGES_RAW + e];
  }
}

__global__ void detect_i64(const int* __restrict__ ei, int* __restrict__ flag) {
  const int lane = threadIdx.x & 63;
  int hi = ei[2 * lane + 1];
  unsigned long long b = __ballot(hi != 0);
  if (lane == 0) *flag = (b == 0ULL) ? 1 : 0;
}

// ---------- CSR build ----------
__global__ __launch_bounds__(256) void count_deg(const int* __restrict__ ei,
                                                 const int* __restrict__ flag,
                                                 int* __restrict__ deg) {
  const int e = blockIdx.x * 256 + threadIdx.x;
  if (e >= E_TOT) return;
  int s, d;
  get_edge(ei, *flag, e, s, d);
  atomicAdd(&deg[d], 1);
}

__global__ __launch_bounds__(256) void scan_a(const int* __restrict__ deg,
                                              int* __restrict__ exc,
                                              int* __restrict__ bsum) {
  __shared__ int wsum[4];
  const int t = threadIdx.x;
  const int base = blockIdx.x * 1024 + t * 4;
  int v[4];
  int s = 0;
#pragma unroll
  for (int i = 0; i < 4; ++i) {
    v[i] = (base + i < N_NODES) ? deg[base + i] : 0;
    s += v[i];
  }
  const int lane = t & 63, wid = t >> 6;
  int sc = s;
#pragma unroll
  for (int m = 1; m < 64; m <<= 1) {
    int o = __shfl_up(sc, m, 64);
    if (lane >= m) sc += o;
  }
  if (lane == 63) wsum[wid] = sc;
  __syncthreads();
  int woff = 0;
  for (int w = 0; w < wid; ++w) woff += wsum[w];
  int run = woff + sc - s;
#pragma unroll
  for (int i = 0; i < 4; ++i) {
    if (base + i < N_NODES) exc[base + i] = run;
    run += v[i];
  }
  if (t == 255) bsum[blockIdx.x] = woff + sc;
}

__global__ __launch_bounds__(64) void scan_b(int* __restrict__ bsum, int nb) {
  const int lane = threadIdx.x;
  int v = (lane < nb) ? bsum[lane] : 0;
  int sc = v;
#pragma unroll
  for (int m = 1; m < 64; m <<= 1) {
    int o = __shfl_up(sc, m, 64);
    if (lane >= m) sc += o;
  }
  if (lane < nb) bsum[lane] = sc - v;
}

__global__ __launch_bounds__(256) void scan_c(const int* __restrict__ exc,
                                              const int* __restrict__ bsum,
                                              int* __restrict__ rp,
                                              int* __restrict__ cursor) {
  const int i = blockIdx.x * 256 + threadIdx.x;
  if (i >= N_NODES) return;
  int r = exc[i] + bsum[i >> 10];
  rp[i] = r;
  cursor[i] = r;
}

__global__ __launch_bounds__(256) void scatter(const int* __restrict__ ei,
                                               const int* __restrict__ flag,
                                               int* __restrict__ cursor,
                                               int* __restrict__ csr_src) {
  const int e = blockIdx.x * 256 + threadIdx.x;
  if (e >= E_TOT) return;
  int s, d;
  get_edge(ei, *flag, e, s, d);
  int pos = atomicAdd(&cursor[d], 1);
  csr_src[pos] = s;
}

// ---------- weight prep: WtX[144][128] bf16 ----------
// c < 128          : W^T                  (WtX[c][k] = W[k][c])
// 128 <= c < 128+H : col = W @ att_src[head c-128]
// 128+H <= c <128+2H: col = W @ att_dst[head c-128-H]
// else             : 0
template <int H>
__global__ __launch_bounds__(256) void prep_w(const float* __restrict__ w,
                                              const float* __restrict__ atts,
                                              const float* __restrict__ attd,
                                              ushort* __restrict__ wtx) {
  const int idx = blockIdx.x * 256 + threadIdx.x;  // c*128 + k
  if (idx >= 144 * 128) return;
  const int c = idx >> 7, k = idx & 127;
  constexpr int C = 128 / H;
  float v;
  if (c < 128) {
    v = w[k * 128 + c];
  } else if (c < 128 + H) {
    const int hd = c - 128;
    float s = 0.f;
    for (int j = 0; j < C; ++j) s += w[k * 128 + hd * C + j] * atts[hd * C + j];
    v = s;
  } else if (c < 128 + 2 * H) {
    const int hd = c - 128 - H;
    float s = 0.f;
    for (int j = 0; j < C; ++j) s += w[k * 128 + hd * C + j] * attd[hd * C + j];
    v = s;
  } else {
    v = 0.f;
  }
  wtx[idx] = f2bf(v);
}

// ---------- MFMA GEMM + fused attention-score columns ----------
// one wave per 16-row tile; 9 col-tiles (128 feature cols + 16 score cols).
// mfma_f32_16x16x32_bf16 layouts: A row=lane&15, k=8*(lane>>4)+i;
// D col=lane&15, row=4*(lane>>4)+reg.
template <int H>
__global__ __launch_bounds__(256) void gemm_att(const float* __restrict__ in,
                                                const ushort* __restrict__ wtx,
                                                ushort* __restrict__ h_bf,
                                                float* __restrict__ a_src,
                                                float* __restrict__ a_dst) {
  const int wid = threadIdx.x >> 6;
  const int lane = threadIdx.x & 63;
  const int tile = blockIdx.x * 4 + wid;
  if (tile >= N_NODES / 16) return;
  const int row0 = tile * 16;
  const int rA = lane & 15;   // A-row / D-col within tile
  const int g = lane >> 4;    // k-group / D-row-group

  f32x4 acc[9];
#pragma unroll
  for (int ct = 0; ct < 9; ++ct) acc[ct] = (f32x4){0.f, 0.f, 0.f, 0.f};

#pragma unroll
  for (int ks = 0; ks < 4; ++ks) {
    const int k0 = ks * 32 + g * 8;
    const float* ap = in + (size_t)(row0 + rA) * DIM + k0;
    float4 a0 = *(const float4*)ap;
    float4 a1 = *(const float4*)(ap + 4);
    bf16x8 af;
    af[0] = (short)f2bf(a0.x); af[1] = (short)f2bf(a0.y);
    af[2] = (short)f2bf(a0.z); af[3] = (short)f2bf(a0.w);
    af[4] = (short)f2bf(a1.x); af[5] = (short)f2bf(a1.y);
    af[6] = (short)f2bf(a1.z); af[7] = (short)f2bf(a1.w);
#pragma unroll
    for (int ct = 0; ct < 9; ++ct) {
      bf16x8 bf = *(const bf16x8*)(wtx + (size_t)(ct * 16 + rA) * 128 + k0);
      acc[ct] = __builtin_amdgcn_mfma_f32_16x16x32_bf16(af, bf, acc[ct], 0, 0, 0);
    }
  }

  // feature store (bf16)
#pragma unroll
  for (int ct = 0; ct < 8; ++ct) {
#pragma unroll
    for (int r = 0; r < 4; ++r) {
      const int row = row0 + g * 4 + r;
      h_bf[(size_t)row * DIM + ct * 16 + rA] = f2bf(acc[ct][r]);
    }
  }
  // score store: col-tile 8 columns 0..2H-1 are [src heads | dst heads]
  if (rA < 2 * H) {
#pragma unroll
    for (int r = 0; r < 4; ++r) {
      const int row = row0 + g * 4 + r;
      if (rA < H)
        a_src[(size_t)row * H + rA] = acc[8][r];
      else
        a_dst[(size_t)row * H + (rA - H)] = acc[8][r];
    }
  }
}

// ---------- fused single-pass softmax + bf16 gather + bias + relu ----------
template <int H>
__global__ __launch_bounds__(256) void node_agg(const int* __restrict__ rp,
                                                const int* __restrict__ deg,
                                                const int* __restrict__ csr_src,
                                                const ushort* __restrict__ h_bf,
                                                const float* __restrict__ a_src,
                                                const float* __restrict__ a_dst,
                                                const float* __restrict__ bias,
                                                float* __restrict__ outp) {
  const int wid = threadIdx.x >> 6;
  const int lane = threadIdx.x & 63;
  const int node = blockIdx.x * 4 + wid;
  if (node >= N_NODES) return;
  constexpr int LPH = (DIM / H) / 2;  // lanes per head
  const int head = lane / LPH;
  const float ad = a_dst[(size_t)node * H + head];
  const int beg = rp[node];
  const int dg = deg[node];
  const int* __restrict__ srcs = csr_src + beg;

  float sden = 0.f, ax = 0.f, ay = 0.f;
#pragma unroll 4
  for (int j = 0; j < dg; ++j) {
    int s = srcs[j];
    float v = a_src[(size_t)s * H + head] + ad;
    v = v > 0.f ? v : NEG_SLOPE * v;
    v = fminf(fmaxf(v, -60.f), 80.f);
    float p = __expf(v);
    uint hv = ((const uint*)(h_bf + (size_t)s * DIM))[lane];
    float hx = __uint_as_float((hv & 0xFFFFu) << 16);
    float hy = __uint_as_float(hv & 0xFFFF0000u);
    sden += p;
    ax += p * hx;
    ay += p * hy;
  }
  const float inv = 1.f / sden;
  float2 bv = ((const float2*)bias)[lane];
  float ox = fmaxf(ax * inv + bv.x, 0.f);
  float oy = fmaxf(ay * inv + bv.y, 0.f);
  ((float2*)(outp + (size_t)node * DIM))[lane] = make_float2(ox, oy);
}

extern "C" void kernel_launch(void* const* d_in, const int* in_sizes, int n_in,
                              void* d_out, int out_size, void* d_ws, size_t ws_size,
                              hipStream_t stream) {
  const float* x   = (const float*)d_in[0];
  const int*   ei  = (const int*)d_in[1];
  const float* W1  = (const float*)d_in[2];
  const float* as1 = (const float*)d_in[3];
  const float* ad1 = (const float*)d_in[4];
  const float* b1  = (const float*)d_in[5];
  const float* W2  = (const float*)d_in[6];
  const float* as2 = (const float*)d_in[7];
  const float* ad2 = (const float*)d_in[8];
  const float* b2  = (const float*)d_in[9];
  float* out = (float*)d_out;

  float* ws = (float*)d_ws;
  const size_t F_H = (size_t)N_NODES * DIM;  // 6.4M elems
  float*  z      = ws;                        // 6,400,000 f32
  ushort* h_bf   = (ushort*)(z + F_H);        // 6.4M bf16 (3.2M f32 slots)
  float*  a_src  = z + F_H + F_H / 2;         // 200,000
  float*  a_dst  = a_src + 200000;            // 200,000
  int*    deg    = (int*)(a_dst + 200000);    // 50,000
  int*    exc    = deg + N_NODES;             // 50,176
  int*    bsum   = exc + 50176;               // 64
  int*    rp     = bsum + 64;                 // 50,000
  int*    cursor = rp + N_NODES;              // 50,000
  int*    csr_src= cursor + N_NODES;          // 850,000
  int*    flag   = csr_src + E_TOT;           // 1
  ushort* wtx1   = (ushort*)(flag + 4);       // 144*128 bf16
  ushort* wtx2   = wtx1 + 144 * 128;          // 144*128 bf16

  const int EB = (E_TOT + 255) / 256;          // 3321
  const int NB_SCAN = (N_NODES + 1023) / 1024; // 49
  const int GB = (N_NODES / 16 + 3) / 4;       // 782

  // ---- CSR build + weight prep ----
  hipLaunchKernelGGL(detect_i64, dim3(1), dim3(64), 0, stream, ei, flag);
  hipMemsetAsync(deg, 0, N_NODES * sizeof(int), stream);
  hipLaunchKernelGGL((prep_w<4>), dim3(72), dim3(256), 0, stream, W1, as1, ad1, wtx1);
  hipLaunchKernelGGL((prep_w<1>), dim3(72), dim3(256), 0, stream, W2, as2, ad2, wtx2);
  hipLaunchKernelGGL(count_deg, dim3(EB), dim3(256), 0, stream, ei, flag, deg);
  hipLaunchKernelGGL(scan_a, dim3(NB_SCAN), dim3(256), 0, stream, deg, exc, bsum);
  hipLaunchKernelGGL(scan_b, dim3(1), dim3(64), 0, stream, bsum, NB_SCAN);
  hipLaunchKernelGGL(scan_c, dim3((N_NODES + 255) / 256), dim3(256), 0, stream,
                     exc, bsum, rp, cursor);
  hipLaunchKernelGGL(scatter, dim3(EB), dim3(256), 0, stream, ei, flag, cursor, csr_src);

  // ---- layer 1: GATConv(128 -> 32, heads=4) ----
  hipLaunchKernelGGL((gemm_att<4>), dim3(GB), dim3(256), 0, stream,
                     x, wtx1, h_bf, a_src, a_dst);
  hipLaunchKernelGGL((node_agg<4>), dim3((N_NODES + 3) / 4), dim3(256), 0, stream,
                     rp, deg, csr_src, h_bf, a_src, a_dst, b1, z);

  // ---- layer 2: GATConv(128 -> 128, heads=1) ----
  hipLaunchKernelGGL((gemm_att<1>), dim3(GB), dim3(256), 0, stream,
                     z, wtx2, h_bf, a_src, a_dst);
  hipLaunchKernelGGL((node_agg<1>), dim3((N_NODES + 3) / 4), dim3(256), 0, stream,
                     rp, deg, csr_src, h_bf, a_src, a_dst, b2, out);
}

// Round 6
// 195.798 us; speedup vs baseline: 6.4181x; 1.2683x over previous
//
#include <hip/hip_runtime.h>
#include <hip/hip_bf16.h>
#include <cstddef>

#define N_NODES 50000
#define N_EDGES_RAW 800000
#define E_TOT (N_EDGES_RAW + N_NODES) /* 850000 */
#define DIM 128
#define NEG_SLOPE 0.2f

#define NBUCK 196            /* ceil(50000/256) buckets of 256 nodes */
#define CHUNK 4096           /* edges per block in bucket passes */
#define NBLK_E ((E_TOT + CHUNK - 1) / CHUNK) /* 208 */

typedef __attribute__((ext_vector_type(8))) short bf16x8;
typedef __attribute__((ext_vector_type(4))) float f32x4;

// round-to-nearest-even f32 -> bf16 bits
__device__ __forceinline__ ushort f2bf(float f) {
  unsigned u = __float_as_uint(f);
  return (ushort)((u + 0x7FFFu + ((u >> 16) & 1u)) >> 16);
}

// ---------- edge fetch robust to int32 vs int64 storage of edge_index ----------
__device__ __forceinline__ void get_edge(const int* __restrict__ ei, int is64,
                                         int e, int& s, int& d) {
  if (e >= N_EDGES_RAW) { s = e - N_EDGES_RAW; d = s; return; }
  if (is64) {
    s = ei[2 * (size_t)e];
    d = ei[2 * ((size_t)N_EDGES_RAW + (size_t)e)];
  } else {
    s = ei[e];
    d = ei[N_EDGES_RAW + e];
  }
}

__global__ void detect_i64(const int* __restrict__ ei, int* __restrict__ flag) {
  const int lane = threadIdx.x & 63;
  int hi = ei[2 * lane + 1];
  unsigned long long b = __ballot(hi != 0);
  if (lane == 0) *flag = (b == 0ULL) ? 1 : 0;
}

// ---------- pass 1: per-bucket counts (LDS histogram, 1 global atomic/bucket/blk) ----
__global__ __launch_bounds__(256) void bucket_count(const int* __restrict__ ei,
                                                    const int* __restrict__ flag,
                                                    int* __restrict__ gbcnt) {
  __shared__ int hist[NBUCK];
  const int t = threadIdx.x;
  if (t < NBUCK) hist[t] = 0;
  __syncthreads();
  const int is64 = *flag;
  const int e0 = blockIdx.x * CHUNK;
#pragma unroll
  for (int i = 0; i < CHUNK / 256; ++i) {
    int e = e0 + i * 256 + t;
    if (e < E_TOT) {
      int s, d;
      get_edge(ei, is64, e, s, d);
      atomicAdd(&hist[d >> 8], 1);
    }
  }
  __syncthreads();
  if (t < NBUCK && hist[t] > 0) atomicAdd(&gbcnt[t], hist[t]);
}

// ---------- pass 2: scan bucket counts -> bstart[NBUCK+1], init gcur ----------
__global__ __launch_bounds__(256) void bucket_scan(const int* __restrict__ gbcnt,
                                                   int* __restrict__ bstart,
                                                   int* __restrict__ gcur) {
  __shared__ int wtot[4];
  const int t = threadIdx.x, lane = t & 63, wid = t >> 6;
  int v = (t < NBUCK) ? gbcnt[t] : 0;
  int sc = v;
#pragma unroll
  for (int m = 1; m < 64; m <<= 1) {
    int o = __shfl_up(sc, m, 64);
    if (lane >= m) sc += o;
  }
  if (lane == 63) wtot[wid] = sc;
  __syncthreads();
  int off = 0;
  for (int w = 0; w < wid; ++w) off += wtot[w];
  int excl = off + sc - v;
  if (t < NBUCK) {
    bstart[t] = excl;
    gcur[t] = excl;
  }
  if (t == 255) bstart[NBUCK] = off + sc;  // grand total == E_TOT
}

// ---------- pass 3: scatter packed (s | d<<16) into bucket-contiguous chunks ----
__global__ __launch_bounds__(256) void bucket_scatter(const int* __restrict__ ei,
                                                      const int* __restrict__ flag,
                                                      int* __restrict__ gcur,
                                                      unsigned* __restrict__ tmp) {
  __shared__ int hist[NBUCK];
  __shared__ int base[NBUCK];
  const int t = threadIdx.x;
  if (t < NBUCK) hist[t] = 0;
  __syncthreads();
  const int is64 = *flag;
  const int e0 = blockIdx.x * CHUNK;
  unsigned pair[CHUNK / 256];
  int rank[CHUNK / 256];
#pragma unroll
  for (int i = 0; i < CHUNK / 256; ++i) {
    int e = e0 + i * 256 + t;
    if (e < E_TOT) {
      int s, d;
      get_edge(ei, is64, e, s, d);
      pair[i] = (unsigned)s | ((unsigned)d << 16);
      rank[i] = atomicAdd(&hist[d >> 8], 1);
    }
  }
  __syncthreads();
  if (t < NBUCK && hist[t] > 0) base[t] = atomicAdd(&gcur[t], hist[t]);
  __syncthreads();
#pragma unroll
  for (int i = 0; i < CHUNK / 256; ++i) {
    int e = e0 + i * 256 + t;
    if (e < E_TOT) {
      int b = (int)(pair[i] >> 24);  // (d>>16)>>8
      tmp[base[b] + rank[i]] = pair[i];
    }
  }
}

// ---------- pass 4: per-bucket counting sort -> csr_src, rp, deg ----------
__global__ __launch_bounds__(256) void bucket_sort(const unsigned* __restrict__ tmp,
                                                   const int* __restrict__ bstart,
                                                   int* __restrict__ csr_src,
                                                   int* __restrict__ rp,
                                                   int* __restrict__ deg) {
  __shared__ int cnt[256];
  __shared__ int cur[256];
  __shared__ int wtot[4];
  const int b = blockIdx.x;
  const int t = threadIdx.x, lane = t & 63, wid = t >> 6;
  const int p0 = bstart[b], p1 = bstart[b + 1];
  cnt[t] = 0;
  __syncthreads();
  for (int j = p0 + t; j < p1; j += 256) {
    unsigned pr = tmp[j];
    atomicAdd(&cnt[(pr >> 16) & 255u], 1);
  }
  __syncthreads();
  // exclusive scan of cnt[256]
  int v = cnt[t];
  int sc = v;
#pragma unroll
  for (int m = 1; m < 64; m <<= 1) {
    int o = __shfl_up(sc, m, 64);
    if (lane >= m) sc += o;
  }
  if (lane == 63) wtot[wid] = sc;
  __syncthreads();
  int off = 0;
  for (int w = 0; w < wid; ++w) off += wtot[w];
  const int excl = off + sc - v;
  const int node = b * 256 + t;
  if (node < N_NODES) {
    deg[node] = v;
    rp[node] = p0 + excl;
  }
  cur[t] = excl;
  __syncthreads();
  for (int j = p0 + t; j < p1; j += 256) {
    unsigned pr = tmp[j];
    int ld = (int)((pr >> 16) & 255u);
    int r = atomicAdd(&cur[ld], 1);
    csr_src[p0 + r] = (int)(pr & 0xFFFFu);
  }
}

// ---------- weight prep: WtX[144][128] bf16 ----------
template <int H>
__global__ __launch_bounds__(256) void prep_w(const float* __restrict__ w,
                                              const float* __restrict__ atts,
                                              const float* __restrict__ attd,
                                              ushort* __restrict__ wtx) {
  const int idx = blockIdx.x * 256 + threadIdx.x;  // c*128 + k
  if (idx >= 144 * 128) return;
  const int c = idx >> 7, k = idx & 127;
  constexpr int C = 128 / H;
  float v;
  if (c < 128) {
    v = w[k * 128 + c];
  } else if (c < 128 + H) {
    const int hd = c - 128;
    float s = 0.f;
    for (int j = 0; j < C; ++j) s += w[k * 128 + hd * C + j] * atts[hd * C + j];
    v = s;
  } else if (c < 128 + 2 * H) {
    const int hd = c - 128 - H;
    float s = 0.f;
    for (int j = 0; j < C; ++j) s += w[k * 128 + hd * C + j] * attd[hd * C + j];
    v = s;
  } else {
    v = 0.f;
  }
  wtx[idx] = f2bf(v);
}

// ---------- MFMA GEMM + fused attention-score columns ----------
template <int H>
__global__ __launch_bounds__(256) void gemm_att(const float* __restrict__ in,
                                                const ushort* __restrict__ wtx,
                                                ushort* __restrict__ h_bf,
                                                float* __restrict__ a_src,
                                                float* __restrict__ a_dst) {
  const int wid = threadIdx.x >> 6;
  const int lane = threadIdx.x & 63;
  const int tile = blockIdx.x * 4 + wid;
  if (tile >= N_NODES / 16) return;
  const int row0 = tile * 16;
  const int rA = lane & 15;
  const int g = lane >> 4;

  f32x4 acc[9];
#pragma unroll
  for (int ct = 0; ct < 9; ++ct) acc[ct] = (f32x4){0.f, 0.f, 0.f, 0.f};

#pragma unroll
  for (int ks = 0; ks < 4; ++ks) {
    const int k0 = ks * 32 + g * 8;
    const float* ap = in + (size_t)(row0 + rA) * DIM + k0;
    float4 a0 = *(const float4*)ap;
    float4 a1 = *(const float4*)(ap + 4);
    bf16x8 af;
    af[0] = (short)f2bf(a0.x); af[1] = (short)f2bf(a0.y);
    af[2] = (short)f2bf(a0.z); af[3] = (short)f2bf(a0.w);
    af[4] = (short)f2bf(a1.x); af[5] = (short)f2bf(a1.y);
    af[6] = (short)f2bf(a1.z); af[7] = (short)f2bf(a1.w);
#pragma unroll
    for (int ct = 0; ct < 9; ++ct) {
      bf16x8 bf = *(const bf16x8*)(wtx + (size_t)(ct * 16 + rA) * 128 + k0);
      acc[ct] = __builtin_amdgcn_mfma_f32_16x16x32_bf16(af, bf, acc[ct], 0, 0, 0);
    }
  }

#pragma unroll
  for (int ct = 0; ct < 8; ++ct) {
#pragma unroll
    for (int r = 0; r < 4; ++r) {
      const int row = row0 + g * 4 + r;
      h_bf[(size_t)row * DIM + ct * 16 + rA] = f2bf(acc[ct][r]);
    }
  }
  if (rA < 2 * H) {
#pragma unroll
    for (int r = 0; r < 4; ++r) {
      const int row = row0 + g * 4 + r;
      if (rA < H)
        a_src[(size_t)row * H + rA] = acc[8][r];
      else
        a_dst[(size_t)row * H + (rA - H)] = acc[8][r];
    }
  }
}

// ---------- fused single-pass softmax + bf16 gather + bias + relu ----------
template <int H>
__global__ __launch_bounds__(256) void node_agg(const int* __restrict__ rp,
                                                const int* __restrict__ deg,
                                                const int* __restrict__ csr_src,
                                                const ushort* __restrict__ h_bf,
                                                const float* __restrict__ a_src,
                                                const float* __restrict__ a_dst,
                                                const float* __restrict__ bias,
                                                float* __restrict__ outp) {
  const int wid = threadIdx.x >> 6;
  const int lane = threadIdx.x & 63;
  const int node = blockIdx.x * 4 + wid;
  if (node >= N_NODES) return;
  constexpr int LPH = (DIM / H) / 2;
  const int head = lane / LPH;
  const float ad = a_dst[(size_t)node * H + head];
  const int beg = rp[node];
  const int dg = deg[node];
  const int* __restrict__ srcs = csr_src + beg;

  float sden = 0.f, ax = 0.f, ay = 0.f;
#pragma unroll 4
  for (int j = 0; j < dg; ++j) {
    int s = srcs[j];
    float v = a_src[(size_t)s * H + head] + ad;
    v = v > 0.f ? v : NEG_SLOPE * v;
    v = fminf(fmaxf(v, -60.f), 80.f);
    float p = __expf(v);
    uint hv = ((const uint*)(h_bf + (size_t)s * DIM))[lane];
    float hx = __uint_as_float((hv & 0xFFFFu) << 16);
    float hy = __uint_as_float(hv & 0xFFFF0000u);
    sden += p;
    ax += p * hx;
    ay += p * hy;
  }
  const float inv = 1.f / sden;
  float2 bv = ((const float2*)bias)[lane];
  float ox = fmaxf(ax * inv + bv.x, 0.f);
  float oy = fmaxf(ay * inv + bv.y, 0.f);
  ((float2*)(outp + (size_t)node * DIM))[lane] = make_float2(ox, oy);
}

extern "C" void kernel_launch(void* const* d_in, const int* in_sizes, int n_in,
                              void* d_out, int out_size, void* d_ws, size_t ws_size,
                              hipStream_t stream) {
  const float* x   = (const float*)d_in[0];
  const int*   ei  = (const int*)d_in[1];
  const float* W1  = (const float*)d_in[2];
  const float* as1 = (const float*)d_in[3];
  const float* ad1 = (const float*)d_in[4];
  const float* b1  = (const float*)d_in[5];
  const float* W2  = (const float*)d_in[6];
  const float* as2 = (const float*)d_in[7];
  const float* ad2 = (const float*)d_in[8];
  const float* b2  = (const float*)d_in[9];
  float* out = (float*)d_out;

  float* ws = (float*)d_ws;
  const size_t F_H = (size_t)N_NODES * DIM;  // 6.4M elems
  float*    z      = ws;                         // 6,400,000 f32
  ushort*   h_bf   = (ushort*)(z + F_H);         // 6.4M bf16 (3.2M slots)
  float*    a_src  = z + F_H + F_H / 2;          // 200,000
  float*    a_dst  = a_src + 200000;             // 200,000
  int*      deg    = (int*)(a_dst + 200000);     // 50,000
  int*      rp     = deg + N_NODES;              // 50,000
  int*      csr_src= rp + N_NODES;               // 850,000
  unsigned* tmp    = (unsigned*)(csr_src + E_TOT); // 850,000
  int*      gbcnt  = (int*)(tmp + E_TOT);        // 256
  int*      bstart = gbcnt + 256;                // 256
  int*      gcur   = bstart + 256;               // 256
  int*      flag   = gcur + 256;                 // 1 (+pad)
  ushort*   wtx1   = (ushort*)(flag + 4);        // 144*128 bf16
  ushort*   wtx2   = wtx1 + 144 * 128;           // 144*128 bf16

  const int GB = (N_NODES / 16 + 3) / 4;  // 782

  // ---- CSR build via 2-level counting sort ----
  hipLaunchKernelGGL(detect_i64, dim3(1), dim3(64), 0, stream, ei, flag);
  hipMemsetAsync(gbcnt, 0, NBUCK * sizeof(int), stream);
  hipLaunchKernelGGL((prep_w<4>), dim3(72), dim3(256), 0, stream, W1, as1, ad1, wtx1);
  hipLaunchKernelGGL((prep_w<1>), dim3(72), dim3(256), 0, stream, W2, as2, ad2, wtx2);
  hipLaunchKernelGGL(bucket_count, dim3(NBLK_E), dim3(256), 0, stream, ei, flag, gbcnt);
  hipLaunchKernelGGL(bucket_scan, dim3(1), dim3(256), 0, stream, gbcnt, bstart, gcur);
  hipLaunchKernelGGL(bucket_scatter, dim3(NBLK_E), dim3(256), 0, stream, ei, flag, gcur, tmp);
  hipLaunchKernelGGL(bucket_sort, dim3(NBUCK), dim3(256), 0, stream,
                     tmp, bstart, csr_src, rp, deg);

  // ---- layer 1: GATConv(128 -> 32, heads=4) ----
  hipLaunchKernelGGL((gemm_att<4>), dim3(GB), dim3(256), 0, stream,
                     x, wtx1, h_bf, a_src, a_dst);
  hipLaunchKernelGGL((node_agg<4>), dim3((N_NODES + 3) / 4), dim3(256), 0, stream,
                     rp, deg, csr_src, h_bf, a_src, a_dst, b1, z);

  // ---- layer 2: GATConv(128 -> 128, heads=1) ----
  hipLaunchKernelGGL((gemm_att<1>), dim3(GB), dim3(256), 0, stream,
                     z, wtx2, h_bf, a_src, a_dst);
  hipLaunchKernelGGL((node_agg<1>), dim3((N_NODES + 3) / 4), dim3(256), 0, stream,
                     rp, deg, csr_src, h_bf, a_src, a_dst, b2, out);
}

// Round 7
// 178.263 us; speedup vs baseline: 7.0494x; 1.0984x over previous
//
#include <hip/hip_runtime.h>
#include <hip/hip_bf16.h>
#include <cstddef>

#define N_NODES 50000
#define N_EDGES_RAW 800000
#define E_TOT (N_EDGES_RAW + N_NODES) /* 850000 */
#define DIM 128
#define NEG_SLOPE 0.2f

#define NBUCK 196            /* ceil(50000/256) buckets of 256 nodes */
#define CHUNK 4096           /* edges per block in bucket passes */
#define NBLK_E ((E_TOT + CHUNK - 1) / CHUNK) /* 208 */

typedef __attribute__((ext_vector_type(8))) short bf16x8;
typedef __attribute__((ext_vector_type(4))) float f32x4;

// round-to-nearest-even f32 -> bf16 bits
__device__ __forceinline__ ushort f2bf(float f) {
  unsigned u = __float_as_uint(f);
  return (ushort)((u + 0x7FFFu + ((u >> 16) & 1u)) >> 16);
}

// ---------- edge fetch robust to int32 vs int64 storage of edge_index ----------
__device__ __forceinline__ void get_edge(const int* __restrict__ ei, int is64,
                                         int e, int& s, int& d) {
  if (e >= N_EDGES_RAW) { s = e - N_EDGES_RAW; d = s; return; }
  if (is64) {
    s = ei[2 * (size_t)e];
    d = ei[2 * ((size_t)N_EDGES_RAW + (size_t)e)];
  } else {
    s = ei[e];
    d = ei[N_EDGES_RAW + e];
  }
}

// inline int64-layout detection: wave 0 ballots high words of first 64 elems
__device__ __forceinline__ int detect_inline(const int* __restrict__ ei,
                                             int* sflag) {
  const int t = threadIdx.x;
  if (t < 64) {
    int hi = ei[2 * t + 1];
    unsigned long long b = __ballot(hi != 0);
    if (t == 0) *sflag = (b == 0ULL) ? 1 : 0;
  }
  __syncthreads();
  return *sflag;
}

// ---------- setup: prep both weight tables + zero bucket counters ----------
// WtX[144][128] bf16: c<128 -> W^T; 128..128+H -> W@att_src; +H..+2H -> W@att_dst.
__device__ __forceinline__ void prep_one(const float* __restrict__ w,
                                         const float* __restrict__ atts,
                                         const float* __restrict__ attd,
                                         ushort* __restrict__ wtx,
                                         int H, int idx) {
  const int c = idx >> 7, k = idx & 127;
  const int C = 128 / H;
  float v;
  if (c < 128) {
    v = w[k * 128 + c];
  } else if (c < 128 + H) {
    const int hd = c - 128;
    float s = 0.f;
    for (int j = 0; j < C; ++j) s += w[k * 128 + hd * C + j] * atts[hd * C + j];
    v = s;
  } else if (c < 128 + 2 * H) {
    const int hd = c - 128 - H;
    float s = 0.f;
    for (int j = 0; j < C; ++j) s += w[k * 128 + hd * C + j] * attd[hd * C + j];
    v = s;
  } else {
    v = 0.f;
  }
  wtx[idx] = f2bf(v);
}

__global__ __launch_bounds__(256) void setup(const float* __restrict__ W1,
                                             const float* __restrict__ as1,
                                             const float* __restrict__ ad1,
                                             ushort* __restrict__ wtx1,
                                             const float* __restrict__ W2,
                                             const float* __restrict__ as2,
                                             const float* __restrict__ ad2,
                                             ushort* __restrict__ wtx2,
                                             int* __restrict__ gbcnt) {
  const int b = blockIdx.x, t = threadIdx.x;
  if (b < 72) {
    prep_one(W1, as1, ad1, wtx1, 4, b * 256 + t);
  } else if (b < 144) {
    prep_one(W2, as2, ad2, wtx2, 1, (b - 72) * 256 + t);
  } else {
    if (t < NBUCK) gbcnt[t] = 0;
  }
}

// ---------- pass 1: per-bucket counts ----------
__global__ __launch_bounds__(256) void bucket_count(const int* __restrict__ ei,
                                                    int* __restrict__ gbcnt) {
  __shared__ int hist[NBUCK];
  __shared__ int sflag;
  const int t = threadIdx.x;
  if (t < NBUCK) hist[t] = 0;
  const int is64 = detect_inline(ei, &sflag);  // has __syncthreads inside
  __syncthreads();
  const int e0 = blockIdx.x * CHUNK;
#pragma unroll
  for (int i = 0; i < CHUNK / 256; ++i) {
    int e = e0 + i * 256 + t;
    if (e < E_TOT) {
      int s, d;
      get_edge(ei, is64, e, s, d);
      atomicAdd(&hist[d >> 8], 1);
    }
  }
  __syncthreads();
  if (t < NBUCK && hist[t] > 0) atomicAdd(&gbcnt[t], hist[t]);
}

// ---------- pass 2: scan bucket counts -> bstart[NBUCK+1], init gcur ----------
__global__ __launch_bounds__(256) void bucket_scan(const int* __restrict__ gbcnt,
                                                   int* __restrict__ bstart,
                                                   int* __restrict__ gcur) {
  __shared__ int wtot[4];
  const int t = threadIdx.x, lane = t & 63, wid = t >> 6;
  int v = (t < NBUCK) ? gbcnt[t] : 0;
  int sc = v;
#pragma unroll
  for (int m = 1; m < 64; m <<= 1) {
    int o = __shfl_up(sc, m, 64);
    if (lane >= m) sc += o;
  }
  if (lane == 63) wtot[wid] = sc;
  __syncthreads();
  int off = 0;
  for (int w = 0; w < wid; ++w) off += wtot[w];
  int excl = off + sc - v;
  if (t < NBUCK) {
    bstart[t] = excl;
    gcur[t] = excl;
  }
  if (t == 255) bstart[NBUCK] = off + sc;
}

// ---------- pass 3: scatter packed (s | d<<16) into bucket chunks ----------
__global__ __launch_bounds__(256) void bucket_scatter(const int* __restrict__ ei,
                                                      int* __restrict__ gcur,
                                                      unsigned* __restrict__ tmp) {
  __shared__ int hist[NBUCK];
  __shared__ int base[NBUCK];
  __shared__ int sflag;
  const int t = threadIdx.x;
  if (t < NBUCK) hist[t] = 0;
  const int is64 = detect_inline(ei, &sflag);
  __syncthreads();
  const int e0 = blockIdx.x * CHUNK;
  unsigned pair[CHUNK / 256];
  int rank[CHUNK / 256];
#pragma unroll
  for (int i = 0; i < CHUNK / 256; ++i) {
    int e = e0 + i * 256 + t;
    if (e < E_TOT) {
      int s, d;
      get_edge(ei, is64, e, s, d);
      pair[i] = (unsigned)s | ((unsigned)d << 16);
      rank[i] = atomicAdd(&hist[d >> 8], 1);
    }
  }
  __syncthreads();
  if (t < NBUCK && hist[t] > 0) base[t] = atomicAdd(&gcur[t], hist[t]);
  __syncthreads();
#pragma unroll
  for (int i = 0; i < CHUNK / 256; ++i) {
    int e = e0 + i * 256 + t;
    if (e < E_TOT) {
      int b = (int)(pair[i] >> 24);
      tmp[base[b] + rank[i]] = pair[i];
    }
  }
}

// ---------- pass 4: per-bucket counting sort -> csr_src, rp, deg ----------
__global__ __launch_bounds__(256) void bucket_sort(const unsigned* __restrict__ tmp,
                                                   const int* __restrict__ bstart,
                                                   int* __restrict__ csr_src,
                                                   int* __restrict__ rp,
                                                   int* __restrict__ deg) {
  __shared__ int cnt[256];
  __shared__ int cur[256];
  __shared__ int wtot[4];
  const int b = blockIdx.x;
  const int t = threadIdx.x, lane = t & 63, wid = t >> 6;
  const int p0 = bstart[b], p1 = bstart[b + 1];
  cnt[t] = 0;
  __syncthreads();
  for (int j = p0 + t; j < p1; j += 256) {
    unsigned pr = tmp[j];
    atomicAdd(&cnt[(pr >> 16) & 255u], 1);
  }
  __syncthreads();
  int v = cnt[t];
  int sc = v;
#pragma unroll
  for (int m = 1; m < 64; m <<= 1) {
    int o = __shfl_up(sc, m, 64);
    if (lane >= m) sc += o;
  }
  if (lane == 63) wtot[wid] = sc;
  __syncthreads();
  int off = 0;
  for (int w = 0; w < wid; ++w) off += wtot[w];
  const int excl = off + sc - v;
  const int node = b * 256 + t;
  if (node < N_NODES) {
    deg[node] = v;
    rp[node] = p0 + excl;
  }
  cur[t] = excl;
  __syncthreads();
  for (int j = p0 + t; j < p1; j += 256) {
    unsigned pr = tmp[j];
    int ld = (int)((pr >> 16) & 255u);
    int r = atomicAdd(&cur[ld], 1);
    csr_src[p0 + r] = (int)(pr & 0xFFFFu);
  }
}

// ---------- MFMA GEMM + fused attention-score columns ----------
template <int H>
__global__ __launch_bounds__(256) void gemm_att(const float* __restrict__ in,
                                                const ushort* __restrict__ wtx,
                                                ushort* __restrict__ h_bf,
                                                float* __restrict__ a_src,
                                                float* __restrict__ a_dst) {
  const int wid = threadIdx.x >> 6;
  const int lane = threadIdx.x & 63;
  const int tile = blockIdx.x * 4 + wid;
  if (tile >= N_NODES / 16) return;
  const int row0 = tile * 16;
  const int rA = lane & 15;
  const int g = lane >> 4;

  f32x4 acc[9];
#pragma unroll
  for (int ct = 0; ct < 9; ++ct) acc[ct] = (f32x4){0.f, 0.f, 0.f, 0.f};

#pragma unroll
  for (int ks = 0; ks < 4; ++ks) {
    const int k0 = ks * 32 + g * 8;
    const float* ap = in + (size_t)(row0 + rA) * DIM + k0;
    float4 a0 = *(const float4*)ap;
    float4 a1 = *(const float4*)(ap + 4);
    bf16x8 af;
    af[0] = (short)f2bf(a0.x); af[1] = (short)f2bf(a0.y);
    af[2] = (short)f2bf(a0.z); af[3] = (short)f2bf(a0.w);
    af[4] = (short)f2bf(a1.x); af[5] = (short)f2bf(a1.y);
    af[6] = (short)f2bf(a1.z); af[7] = (short)f2bf(a1.w);
#pragma unroll
    for (int ct = 0; ct < 9; ++ct) {
      bf16x8 bf = *(const bf16x8*)(wtx + (size_t)(ct * 16 + rA) * 128 + k0);
      acc[ct] = __builtin_amdgcn_mfma_f32_16x16x32_bf16(af, bf, acc[ct], 0, 0, 0);
    }
  }

#pragma unroll
  for (int ct = 0; ct < 8; ++ct) {
#pragma unroll
    for (int r = 0; r < 4; ++r) {
      const int row = row0 + g * 4 + r;
      h_bf[(size_t)row * DIM + ct * 16 + rA] = f2bf(acc[ct][r]);
    }
  }
  if (rA < 2 * H) {
#pragma unroll
    for (int r = 0; r < 4; ++r) {
      const int row = row0 + g * 4 + r;
      if (rA < H)
        a_src[(size_t)row * H + rA] = acc[8][r];
      else
        a_dst[(size_t)row * H + (rA - H)] = acc[8][r];
    }
  }
}

// ---------- fused single-pass softmax + gather + bias + relu ----------
// 2 edges/iter: lanes 0-31 own edge j, lanes 32-63 own edge j+1.
// each lane loads 8B (4 bf16 features: 4*(lane&31) .. +3) of its row.
template <int H>
__global__ __launch_bounds__(256) void node_agg(const int* __restrict__ rp,
                                                const int* __restrict__ deg,
                                                const int* __restrict__ csr_src,
                                                const ushort* __restrict__ h_bf,
                                                const float* __restrict__ a_src,
                                                const float* __restrict__ a_dst,
                                                const float* __restrict__ bias,
                                                float* __restrict__ outp) {
  const int wid = threadIdx.x >> 6;
  const int lane = threadIdx.x & 63;
  const int node = blockIdx.x * 4 + wid;
  if (node >= N_NODES) return;
  const int hl = lane & 31;                      // position within half-wave
  const int head = (H == 4) ? (hl >> 3) : 0;     // feature 4*hl -> head
  const float ad = a_dst[(size_t)node * H + head];
  const int beg = rp[node];
  const int dg = deg[node];
  const int* __restrict__ srcs = csr_src + beg;

  float sden = 0.f;
  float a0 = 0.f, a1 = 0.f, a2 = 0.f, a3 = 0.f;

  const int dg2 = dg & ~1;
#pragma unroll 2
  for (int j = 0; j < dg2; j += 2) {
    int s = srcs[j + (lane >> 5)];  // half 0 -> edge j, half 1 -> edge j+1
    float v = a_src[(size_t)s * H + head] + ad;
    v = v > 0.f ? v : NEG_SLOPE * v;
    v = fminf(fmaxf(v, -60.f), 80.f);
    float p = __expf(v);
    uint2 hv = ((const uint2*)(h_bf + (size_t)s * DIM))[hl];
    float h0 = __uint_as_float((hv.x & 0xFFFFu) << 16);
    float h1 = __uint_as_float(hv.x & 0xFFFF0000u);
    float h2 = __uint_as_float((hv.y & 0xFFFFu) << 16);
    float h3 = __uint_as_float(hv.y & 0xFFFF0000u);
    sden += p;
    a0 += p * h0; a1 += p * h1; a2 += p * h2; a3 += p * h3;
  }
  if (dg & 1) {
    int s = srcs[dg - 1];
    float v = a_src[(size_t)s * H + head] + ad;
    v = v > 0.f ? v : NEG_SLOPE * v;
    v = fminf(fmaxf(v, -60.f), 80.f);
    float p = __expf(v);
    if (lane >= 32) p = 0.f;  // only half 0 counts the tail edge
    uint2 hv = ((const uint2*)(h_bf + (size_t)s * DIM))[hl];
    float h0 = __uint_as_float((hv.x & 0xFFFFu) << 16);
    float h1 = __uint_as_float(hv.x & 0xFFFF0000u);
    float h2 = __uint_as_float((hv.y & 0xFFFFu) << 16);
    float h3 = __uint_as_float(hv.y & 0xFFFF0000u);
    sden += p;
    a0 += p * h0; a1 += p * h1; a2 += p * h2; a3 += p * h3;
  }

  // merge half-wave partials (lane i <-> lane i+32 hold same features)
  sden += __shfl_xor(sden, 32);
  a0 += __shfl_xor(a0, 32);
  a1 += __shfl_xor(a1, 32);
  a2 += __shfl_xor(a2, 32);
  a3 += __shfl_xor(a3, 32);

  if (lane < 32) {
    const float inv = 1.f / sden;
    float4 bv = ((const float4*)bias)[hl];
    float4 o;
    o.x = fmaxf(a0 * inv + bv.x, 0.f);
    o.y = fmaxf(a1 * inv + bv.y, 0.f);
    o.z = fmaxf(a2 * inv + bv.z, 0.f);
    o.w = fmaxf(a3 * inv + bv.w, 0.f);
    ((float4*)(outp + (size_t)node * DIM))[hl] = o;
  }
}

extern "C" void kernel_launch(void* const* d_in, const int* in_sizes, int n_in,
                              void* d_out, int out_size, void* d_ws, size_t ws_size,
                              hipStream_t stream) {
  const float* x   = (const float*)d_in[0];
  const int*   ei  = (const int*)d_in[1];
  const float* W1  = (const float*)d_in[2];
  const float* as1 = (const float*)d_in[3];
  const float* ad1 = (const float*)d_in[4];
  const float* b1  = (const float*)d_in[5];
  const float* W2  = (const float*)d_in[6];
  const float* as2 = (const float*)d_in[7];
  const float* ad2 = (const float*)d_in[8];
  const float* b2  = (const float*)d_in[9];
  float* out = (float*)d_out;

  float* ws = (float*)d_ws;
  const size_t F_H = (size_t)N_NODES * DIM;  // 6.4M elems
  float*    z      = ws;                           // 6,400,000 f32
  ushort*   h_bf   = (ushort*)(z + F_H);           // 6.4M bf16 (3.2M slots)
  float*    a_src  = z + F_H + F_H / 2;            // 200,000
  float*    a_dst  = a_src + 200000;               // 200,000
  int*      deg    = (int*)(a_dst + 200000);       // 50,000
  int*      rp     = deg + N_NODES;                // 50,000
  int*      csr_src= rp + N_NODES;                 // 850,000
  unsigned* tmp    = (unsigned*)(csr_src + E_TOT); // 850,000
  int*      gbcnt  = (int*)(tmp + E_TOT);          // 256
  int*      bstart = gbcnt + 256;                  // 256
  int*      gcur   = bstart + 256;                 // 256
  ushort*   wtx1   = (ushort*)(gcur + 256);        // 144*128 bf16
  ushort*   wtx2   = wtx1 + 144 * 128;             // 144*128 bf16

  const int GB = (N_NODES / 16 + 3) / 4;  // 782

  // ---- setup + CSR build via 2-level counting sort ----
  hipLaunchKernelGGL(setup, dim3(145), dim3(256), 0, stream,
                     W1, as1, ad1, wtx1, W2, as2, ad2, wtx2, gbcnt);
  hipLaunchKernelGGL(bucket_count, dim3(NBLK_E), dim3(256), 0, stream, ei, gbcnt);
  hipLaunchKernelGGL(bucket_scan, dim3(1), dim3(256), 0, stream, gbcnt, bstart, gcur);
  hipLaunchKernelGGL(bucket_scatter, dim3(NBLK_E), dim3(256), 0, stream, ei, gcur, tmp);
  hipLaunchKernelGGL(bucket_sort, dim3(NBUCK), dim3(256), 0, stream,
                     tmp, bstart, csr_src, rp, deg);

  // ---- layer 1: GATConv(128 -> 32, heads=4) ----
  hipLaunchKernelGGL((gemm_att<4>), dim3(GB), dim3(256), 0, stream,
                     x, wtx1, h_bf, a_src, a_dst);
  hipLaunchKernelGGL((node_agg<4>), dim3((N_NODES + 3) / 4), dim3(256), 0, stream,
                     rp, deg, csr_src, h_bf, a_src, a_dst, b1, z);

  // ---- layer 2: GATConv(128 -> 128, heads=1) ----
  hipLaunchKernelGGL((gemm_att<1>), dim3(GB), dim3(256), 0, stream,
                     z, wtx2, h_bf, a_src, a_dst);
  hipLaunchKernelGGL((node_agg<1>), dim3((N_NODES + 3) / 4), dim3(256), 0, stream,
                     rp, deg, csr_src, h_bf, a_src, a_dst, b2, out);
}

// Round 8
// 169.630 us; speedup vs baseline: 7.4082x; 1.0509x over previous
//
#include <hip/hip_runtime.h>
#include <hip/hip_bf16.h>
#include <cstddef>

#define N_NODES 50000
#define N_EDGES_RAW 800000
#define E_TOT (N_EDGES_RAW + N_NODES) /* 850000 */
#define DIM 128
#define NEG_SLOPE 0.2f

#define NBUCK 196            /* ceil(50000/256) buckets of 256 nodes */
#define CHUNK 4096           /* edges per block in bucket passes */
#define NBLK_E ((E_TOT + CHUNK - 1) / CHUNK) /* 208 */
#define CONV_BLKS 3125       /* 6.4M f32 -> bf16, 2048 elems/block */

typedef __attribute__((ext_vector_type(8))) short bf16x8;
typedef __attribute__((ext_vector_type(4))) float f32x4;

// round-to-nearest-even f32 -> bf16 bits
__device__ __forceinline__ ushort f2bf(float f) {
  unsigned u = __float_as_uint(f);
  return (ushort)((u + 0x7FFFu + ((u >> 16) & 1u)) >> 16);
}
__device__ __forceinline__ float bf2f_lo(uint u) {
  return __uint_as_float(u << 16);
}
__device__ __forceinline__ float bf2f_hi(uint u) {
  return __uint_as_float(u & 0xFFFF0000u);
}

// ---------- edge fetch robust to int32 vs int64 storage of edge_index ----------
__device__ __forceinline__ void get_edge(const int* __restrict__ ei, int is64,
                                         int e, int& s, int& d) {
  if (e >= N_EDGES_RAW) { s = e - N_EDGES_RAW; d = s; return; }
  if (is64) {
    s = ei[2 * (size_t)e];
    d = ei[2 * ((size_t)N_EDGES_RAW + (size_t)e)];
  } else {
    s = ei[e];
    d = ei[N_EDGES_RAW + e];
  }
}

// inline int64-layout detection: first wave ballots high words of first 64 elems
__device__ __forceinline__ int detect_inline(const int* __restrict__ ei,
                                             int* sflag) {
  const int t = threadIdx.x;
  if (t < 64) {
    int hi = ei[2 * t + 1];
    unsigned long long b = __ballot(hi != 0);
    if (t == 0) *sflag = (b == 0ULL) ? 1 : 0;
  }
  __syncthreads();
  return *sflag;
}

// ---------- WtX[144][128] bf16 prep ----------
// c<128 -> W^T; 128..128+H -> W@att_src; +H..+2H -> W@att_dst; else 0.
__device__ __forceinline__ void prep_one(const float* __restrict__ w,
                                         const float* __restrict__ atts,
                                         const float* __restrict__ attd,
                                         ushort* __restrict__ wtx,
                                         int H, int idx) {
  const int c = idx >> 7, k = idx & 127;
  const int C = 128 / H;
  float v;
  if (c < 128) {
    v = w[k * 128 + c];
  } else if (c < 128 + H) {
    const int hd = c - 128;
    float s = 0.f;
    for (int j = 0; j < C; ++j) s += w[k * 128 + hd * C + j] * atts[hd * C + j];
    v = s;
  } else if (c < 128 + 2 * H) {
    const int hd = c - 128 - H;
    float s = 0.f;
    for (int j = 0; j < C; ++j) s += w[k * 128 + hd * C + j] * attd[hd * C + j];
    v = s;
  } else {
    v = 0.f;
  }
  wtx[idx] = f2bf(v);
}

// ---------- mega setup: wtx prep | x->bf16 convert | bucket count ----------
// block roles: [0,72) wtx1, [72,144) wtx2, [144,144+CONV) convert,
// [144+CONV, 144+CONV+NBLK_E) per-block bucket histogram -> hist_mat (no atomics)
__global__ __launch_bounds__(256) void mega_setup(
    const float* __restrict__ W1, const float* __restrict__ as1,
    const float* __restrict__ ad1, ushort* __restrict__ wtx1,
    const float* __restrict__ W2, const float* __restrict__ as2,
    const float* __restrict__ ad2, ushort* __restrict__ wtx2,
    const float* __restrict__ x, ushort* __restrict__ x_bf,
    const int* __restrict__ ei, int* __restrict__ hist_mat) {
  const int b = blockIdx.x, t = threadIdx.x;
  if (b < 72) {
    prep_one(W1, as1, ad1, wtx1, 4, b * 256 + t);
  } else if (b < 144) {
    prep_one(W2, as2, ad2, wtx2, 1, (b - 72) * 256 + t);
  } else if (b < 144 + CONV_BLKS) {
    const int base = (b - 144) * 2048 + t * 8;
    float4 v0 = *(const float4*)(x + base);
    float4 v1 = *(const float4*)(x + base + 4);
    ushort u[8];
    u[0] = f2bf(v0.x); u[1] = f2bf(v0.y); u[2] = f2bf(v0.z); u[3] = f2bf(v0.w);
    u[4] = f2bf(v1.x); u[5] = f2bf(v1.y); u[6] = f2bf(v1.z); u[7] = f2bf(v1.w);
    *(uint4*)(x_bf + base) = *(const uint4*)u;
  } else {
    __shared__ int hist[NBUCK];
    __shared__ int sflag;
    const int cb = b - 144 - CONV_BLKS;
    if (t < NBUCK) hist[t] = 0;
    const int is64 = detect_inline(ei, &sflag);  // has __syncthreads
    __syncthreads();
    const int e0 = cb * CHUNK;
#pragma unroll
    for (int i = 0; i < CHUNK / 256; ++i) {
      int e = e0 + i * 256 + t;
      if (e < E_TOT) {
        int s, d;
        get_edge(ei, is64, e, s, d);
        atomicAdd(&hist[d >> 8], 1);
      }
    }
    __syncthreads();
    if (t < NBUCK) hist_mat[cb * NBUCK + t] = hist[t];
  }
}

// ---------- scan: column-sum hist_mat -> bstart[NBUCK+1], init gcur ----------
__global__ __launch_bounds__(256) void bucket_scan(const int* __restrict__ hist_mat,
                                                   int* __restrict__ bstart,
                                                   int* __restrict__ gcur) {
  __shared__ int wtot[4];
  const int t = threadIdx.x, lane = t & 63, wid = t >> 6;
  int v = 0;
  if (t < NBUCK)
    for (int b = 0; b < NBLK_E; ++b) v += hist_mat[b * NBUCK + t];
  int sc = v;
#pragma unroll
  for (int m = 1; m < 64; m <<= 1) {
    int o = __shfl_up(sc, m, 64);
    if (lane >= m) sc += o;
  }
  if (lane == 63) wtot[wid] = sc;
  __syncthreads();
  int off = 0;
  for (int w = 0; w < wid; ++w) off += wtot[w];
  int excl = off + sc - v;
  if (t < NBUCK) {
    bstart[t] = excl;
    gcur[t] = excl;
  }
  if (t == 255) bstart[NBUCK] = off + sc;
}

// ---------- scatter packed (s | d<<16) into bucket chunks ----------
__global__ __launch_bounds__(256) void bucket_scatter(const int* __restrict__ ei,
                                                      int* __restrict__ gcur,
                                                      unsigned* __restrict__ tmp) {
  __shared__ int hist[NBUCK];
  __shared__ int base[NBUCK];
  __shared__ int sflag;
  const int t = threadIdx.x;
  if (t < NBUCK) hist[t] = 0;
  const int is64 = detect_inline(ei, &sflag);
  __syncthreads();
  const int e0 = blockIdx.x * CHUNK;
  unsigned pair[CHUNK / 256];
  int rank[CHUNK / 256];
#pragma unroll
  for (int i = 0; i < CHUNK / 256; ++i) {
    int e = e0 + i * 256 + t;
    if (e < E_TOT) {
      int s, d;
      get_edge(ei, is64, e, s, d);
      pair[i] = (unsigned)s | ((unsigned)d << 16);
      rank[i] = atomicAdd(&hist[d >> 8], 1);
    }
  }
  __syncthreads();
  if (t < NBUCK && hist[t] > 0) base[t] = atomicAdd(&gcur[t], hist[t]);
  __syncthreads();
#pragma unroll
  for (int i = 0; i < CHUNK / 256; ++i) {
    int e = e0 + i * 256 + t;
    if (e < E_TOT) {
      int b = (int)(pair[i] >> 24);
      tmp[base[b] + rank[i]] = pair[i];
    }
  }
}

// ---------- per-bucket counting sort -> csr_src, rp, deg ----------
__global__ __launch_bounds__(256) void bucket_sort(const unsigned* __restrict__ tmp,
                                                   const int* __restrict__ bstart,
                                                   int* __restrict__ csr_src,
                                                   int* __restrict__ rp,
                                                   int* __restrict__ deg) {
  __shared__ int cnt[256];
  __shared__ int cur[256];
  __shared__ int wtot[4];
  const int b = blockIdx.x;
  const int t = threadIdx.x, lane = t & 63, wid = t >> 6;
  const int p0 = bstart[b], p1 = bstart[b + 1];
  cnt[t] = 0;
  __syncthreads();
  for (int j = p0 + t; j < p1; j += 256) {
    unsigned pr = tmp[j];
    atomicAdd(&cnt[(pr >> 16) & 255u], 1);
  }
  __syncthreads();
  int v = cnt[t];
  int sc = v;
#pragma unroll
  for (int m = 1; m < 64; m <<= 1) {
    int o = __shfl_up(sc, m, 64);
    if (lane >= m) sc += o;
  }
  if (lane == 63) wtot[wid] = sc;
  __syncthreads();
  int off = 0;
  for (int w = 0; w < wid; ++w) off += wtot[w];
  const int excl = off + sc - v;
  const int node = b * 256 + t;
  if (node < N_NODES) {
    deg[node] = v;
    rp[node] = p0 + excl;
  }
  cur[t] = excl;
  __syncthreads();
  for (int j = p0 + t; j < p1; j += 256) {
    unsigned pr = tmp[j];
    int ld = (int)((pr >> 16) & 255u);
    int r = atomicAdd(&cur[ld], 1);
    csr_src[p0 + r] = (int)(pr & 0xFFFFu);
  }
}

// ---------- MFMA GEMM (bf16 in) + fused attention-score columns ----------
template <int H>
__global__ __launch_bounds__(256) void gemm_att(const ushort* __restrict__ in_bf,
                                                const ushort* __restrict__ wtx,
                                                ushort* __restrict__ h_bf,
                                                float* __restrict__ a_src,
                                                float* __restrict__ a_dst) {
  const int wid = threadIdx.x >> 6;
  const int lane = threadIdx.x & 63;
  const int tile = blockIdx.x * 4 + wid;
  if (tile >= N_NODES / 16) return;
  const int row0 = tile * 16;
  const int rA = lane & 15;
  const int g = lane >> 4;

  f32x4 acc[9];
#pragma unroll
  for (int ct = 0; ct < 9; ++ct) acc[ct] = (f32x4){0.f, 0.f, 0.f, 0.f};

#pragma unroll
  for (int ks = 0; ks < 4; ++ks) {
    const int k0 = ks * 32 + g * 8;
    bf16x8 af = *(const bf16x8*)(in_bf + (size_t)(row0 + rA) * DIM + k0);
#pragma unroll
    for (int ct = 0; ct < 9; ++ct) {
      bf16x8 bf = *(const bf16x8*)(wtx + (size_t)(ct * 16 + rA) * 128 + k0);
      acc[ct] = __builtin_amdgcn_mfma_f32_16x16x32_bf16(af, bf, acc[ct], 0, 0, 0);
    }
  }

#pragma unroll
  for (int ct = 0; ct < 8; ++ct) {
#pragma unroll
    for (int r = 0; r < 4; ++r) {
      const int row = row0 + g * 4 + r;
      h_bf[(size_t)row * DIM + ct * 16 + rA] = f2bf(acc[ct][r]);
    }
  }
  if (rA < 2 * H) {
#pragma unroll
    for (int r = 0; r < 4; ++r) {
      const int row = row0 + g * 4 + r;
      if (rA < H)
        a_src[(size_t)row * H + rA] = acc[8][r];
      else
        a_dst[(size_t)row * H + (rA - H)] = acc[8][r];
    }
  }
}

// ---------- fused single-pass softmax + gather + bias + relu ----------
// 4 edges/iter: quarter-wave (16 lanes) per edge, uint4 (8 bf16) per lane.
template <int H, bool OBF>
__global__ __launch_bounds__(256) void node_agg(const int* __restrict__ rp,
                                                const int* __restrict__ deg,
                                                const int* __restrict__ csr_src,
                                                const ushort* __restrict__ h_bf,
                                                const float* __restrict__ a_src,
                                                const float* __restrict__ a_dst,
                                                const float* __restrict__ bias,
                                                void* __restrict__ outp) {
  const int wid = threadIdx.x >> 6;
  const int lane = threadIdx.x & 63;
  const int node = blockIdx.x * 4 + wid;
  if (node >= N_NODES) return;
  const int ql = lane >> 4;                    // quarter 0..3 -> edge j+ql
  const int hl = lane & 15;                    // features 8*hl .. 8*hl+7
  const int head = (H == 4) ? (hl >> 2) : 0;
  const float ad = a_dst[(size_t)node * H + head];
  const int beg = rp[node];
  const int dg = deg[node];
  const int* __restrict__ srcs = csr_src + beg;

  float sden = 0.f;
  float a0 = 0.f, a1 = 0.f, a2 = 0.f, a3 = 0.f;
  float a4 = 0.f, a5 = 0.f, a6 = 0.f, a7 = 0.f;

  int j = 0;
#pragma unroll 2
  for (; j + 4 <= dg; j += 4) {
    int s = srcs[j + ql];
    float v = a_src[(size_t)s * H + head] + ad;
    v = v > 0.f ? v : NEG_SLOPE * v;
    v = fminf(fmaxf(v, -60.f), 80.f);
    float p = __expf(v);
    uint4 hv = ((const uint4*)(h_bf + (size_t)s * DIM))[hl];
    sden += p;
    a0 += p * bf2f_lo(hv.x); a1 += p * bf2f_hi(hv.x);
    a2 += p * bf2f_lo(hv.y); a3 += p * bf2f_hi(hv.y);
    a4 += p * bf2f_lo(hv.z); a5 += p * bf2f_hi(hv.z);
    a6 += p * bf2f_lo(hv.w); a7 += p * bf2f_hi(hv.w);
  }
  if (j < dg) {  // masked tail (1..3 edges)
    int jj = j + ql;
    int s = srcs[jj < dg ? jj : (dg - 1)];
    float v = a_src[(size_t)s * H + head] + ad;
    v = v > 0.f ? v : NEG_SLOPE * v;
    v = fminf(fmaxf(v, -60.f), 80.f);
    float p = (jj < dg) ? __expf(v) : 0.f;
    uint4 hv = ((const uint4*)(h_bf + (size_t)s * DIM))[hl];
    sden += p;
    a0 += p * bf2f_lo(hv.x); a1 += p * bf2f_hi(hv.x);
    a2 += p * bf2f_lo(hv.y); a3 += p * bf2f_hi(hv.y);
    a4 += p * bf2f_lo(hv.z); a5 += p * bf2f_hi(hv.z);
    a6 += p * bf2f_lo(hv.w); a7 += p * bf2f_hi(hv.w);
  }

  // merge quarters (lane i, i^16, i^32, i^48 hold the same features)
#pragma unroll
  for (int m = 32; m >= 16; m >>= 1) {
    sden += __shfl_xor(sden, m);
    a0 += __shfl_xor(a0, m); a1 += __shfl_xor(a1, m);
    a2 += __shfl_xor(a2, m); a3 += __shfl_xor(a3, m);
    a4 += __shfl_xor(a4, m); a5 += __shfl_xor(a5, m);
    a6 += __shfl_xor(a6, m); a7 += __shfl_xor(a7, m);
  }

  if (lane < 16) {
    const float inv = 1.f / sden;
    float4 bv0 = ((const float4*)bias)[2 * hl];
    float4 bv1 = ((const float4*)bias)[2 * hl + 1];
    float o0 = fmaxf(a0 * inv + bv0.x, 0.f);
    float o1 = fmaxf(a1 * inv + bv0.y, 0.f);
    float o2 = fmaxf(a2 * inv + bv0.z, 0.f);
    float o3 = fmaxf(a3 * inv + bv0.w, 0.f);
    float o4 = fmaxf(a4 * inv + bv1.x, 0.f);
    float o5 = fmaxf(a5 * inv + bv1.y, 0.f);
    float o6 = fmaxf(a6 * inv + bv1.z, 0.f);
    float o7 = fmaxf(a7 * inv + bv1.w, 0.f);
    if (OBF) {
      ushort u[8] = {f2bf(o0), f2bf(o1), f2bf(o2), f2bf(o3),
                     f2bf(o4), f2bf(o5), f2bf(o6), f2bf(o7)};
      ((uint4*)((ushort*)outp + (size_t)node * DIM))[hl] = *(const uint4*)u;
    } else {
      float* op = (float*)outp + (size_t)node * DIM;
      ((float4*)op)[2 * hl] = make_float4(o0, o1, o2, o3);
      ((float4*)op)[2 * hl + 1] = make_float4(o4, o5, o6, o7);
    }
  }
}

extern "C" void kernel_launch(void* const* d_in, const int* in_sizes, int n_in,
                              void* d_out, int out_size, void* d_ws, size_t ws_size,
                              hipStream_t stream) {
  const float* x   = (const float*)d_in[0];
  const int*   ei  = (const int*)d_in[1];
  const float* W1  = (const float*)d_in[2];
  const float* as1 = (const float*)d_in[3];
  const float* ad1 = (const float*)d_in[4];
  const float* b1  = (const float*)d_in[5];
  const float* W2  = (const float*)d_in[6];
  const float* as2 = (const float*)d_in[7];
  const float* ad2 = (const float*)d_in[8];
  const float* b2  = (const float*)d_in[9];
  float* out = (float*)d_out;

  char* ws = (char*)d_ws;
  const size_t F_H = (size_t)N_NODES * DIM;  // 6.4M elems
  ushort* h_bf    = (ushort*)ws;                       // 12.8 MB
  ushort* z_bf    = h_bf + F_H;                        // 12.8 MB
  ushort* x_bf    = z_bf + F_H;                        // 12.8 MB
  float*  a_src   = (float*)(x_bf + F_H);              // 800 KB
  float*  a_dst   = a_src + 200000;                    // 800 KB
  int*    deg     = (int*)(a_dst + 200000);            // 200 KB
  int*    rp      = deg + N_NODES;                     // 200 KB
  int*    csr_src = rp + N_NODES;                      // 3.4 MB
  unsigned* tmp   = (unsigned*)(csr_src + E_TOT);      // 3.4 MB
  int*    hist_mat= (int*)(tmp + E_TOT);               // 208*196*4 = 163 KB
  int*    bstart  = hist_mat + NBLK_E * NBUCK;         // 197
  int*    gcur    = bstart + NBUCK + 1;                // 196
  ushort* wtx1    = (ushort*)(gcur + NBUCK + 3);       // 36 KB
  ushort* wtx2    = wtx1 + 144 * 128;                  // 36 KB

  const int GB = (N_NODES / 16 + 3) / 4;  // 782
  const int MEGA = 144 + CONV_BLKS + NBLK_E;

  hipLaunchKernelGGL(mega_setup, dim3(MEGA), dim3(256), 0, stream,
                     W1, as1, ad1, wtx1, W2, as2, ad2, wtx2, x, x_bf, ei, hist_mat);
  hipLaunchKernelGGL(bucket_scan, dim3(1), dim3(256), 0, stream,
                     hist_mat, bstart, gcur);
  hipLaunchKernelGGL(bucket_scatter, dim3(NBLK_E), dim3(256), 0, stream,
                     ei, gcur, tmp);
  hipLaunchKernelGGL(bucket_sort, dim3(NBUCK), dim3(256), 0, stream,
                     tmp, bstart, csr_src, rp, deg);

  // ---- layer 1: GATConv(128 -> 32, heads=4) ----
  hipLaunchKernelGGL((gemm_att<4>), dim3(GB), dim3(256), 0, stream,
                     x_bf, wtx1, h_bf, a_src, a_dst);
  hipLaunchKernelGGL((node_agg<4, true>), dim3((N_NODES + 3) / 4), dim3(256), 0,
                     stream, rp, deg, csr_src, h_bf, a_src, a_dst, b1, z_bf);

  // ---- layer 2: GATConv(128 -> 128, heads=1) ----
  hipLaunchKernelGGL((gemm_att<1>), dim3(GB), dim3(256), 0, stream,
                     z_bf, wtx2, h_bf, a_src, a_dst);
  hipLaunchKernelGGL((node_agg<1, false>), dim3((N_NODES + 3) / 4), dim3(256), 0,
                     stream, rp, deg, csr_src, h_bf, a_src, a_dst, b2, out);
}

// Round 9
// 164.461 us; speedup vs baseline: 7.6410x; 1.0314x over previous
//
#include <hip/hip_runtime.h>
#include <hip/hip_bf16.h>
#include <cstddef>

#define N_NODES 50000
#define N_EDGES_RAW 800000
#define E_TOT (N_EDGES_RAW + N_NODES) /* 850000 */
#define DIM 128
#define NEG_SLOPE 0.2f

#define NBUCK 196            /* ceil(50000/256) buckets of 256 nodes */
#define CHUNK 4096           /* edges per block in bucket passes */
#define NBLK_E ((E_TOT + CHUNK - 1) / CHUNK) /* 208 */
#define CONV_BLKS 3125       /* 6.4M f32 -> bf16, 2048 elems/block */
#define GB 782               /* gemm blocks: ceil(3125 tiles / 4 waves) */

typedef __attribute__((ext_vector_type(8))) short bf16x8;
typedef __attribute__((ext_vector_type(4))) float f32x4;

// round-to-nearest-even f32 -> bf16 bits
__device__ __forceinline__ ushort f2bf(float f) {
  unsigned u = __float_as_uint(f);
  return (ushort)((u + 0x7FFFu + ((u >> 16) & 1u)) >> 16);
}
__device__ __forceinline__ float bf2f_lo(uint u) {
  return __uint_as_float(u << 16);
}
__device__ __forceinline__ float bf2f_hi(uint u) {
  return __uint_as_float(u & 0xFFFF0000u);
}

// ---------- edge fetch robust to int32 vs int64 storage of edge_index ----------
__device__ __forceinline__ void get_edge(const int* __restrict__ ei, int is64,
                                         int e, int& s, int& d) {
  if (e >= N_EDGES_RAW) { s = e - N_EDGES_RAW; d = s; return; }
  if (is64) {
    s = ei[2 * (size_t)e];
    d = ei[2 * ((size_t)N_EDGES_RAW + (size_t)e)];
  } else {
    s = ei[e];
    d = ei[N_EDGES_RAW + e];
  }
}

__device__ __forceinline__ int detect_inline(const int* __restrict__ ei,
                                             int* sflag) {
  const int t = threadIdx.x;
  if (t < 64) {
    int hi = ei[2 * t + 1];
    unsigned long long b = __ballot(hi != 0);
    if (t == 0) *sflag = (b == 0ULL) ? 1 : 0;
  }
  __syncthreads();
  return *sflag;
}

// ---------- WtX[144][128] bf16 prep ----------
__device__ __forceinline__ void prep_one(const float* __restrict__ w,
                                         const float* __restrict__ atts,
                                         const float* __restrict__ attd,
                                         ushort* __restrict__ wtx,
                                         int H, int idx) {
  const int c = idx >> 7, k = idx & 127;
  const int C = 128 / H;
  float v;
  if (c < 128) {
    v = w[k * 128 + c];
  } else if (c < 128 + H) {
    const int hd = c - 128;
    float s = 0.f;
    for (int j = 0; j < C; ++j) s += w[k * 128 + hd * C + j] * atts[hd * C + j];
    v = s;
  } else if (c < 128 + 2 * H) {
    const int hd = c - 128 - H;
    float s = 0.f;
    for (int j = 0; j < C; ++j) s += w[k * 128 + hd * C + j] * attd[hd * C + j];
    v = s;
  } else {
    v = 0.f;
  }
  wtx[idx] = f2bf(v);
}

// ---------- mega setup: wtx prep | x->bf16 | per-block histogram + pair pack ----
__global__ __launch_bounds__(256) void mega_setup(
    const float* __restrict__ W1, const float* __restrict__ as1,
    const float* __restrict__ ad1, ushort* __restrict__ wtx1,
    const float* __restrict__ W2, const float* __restrict__ as2,
    const float* __restrict__ ad2, ushort* __restrict__ wtx2,
    const float* __restrict__ x, ushort* __restrict__ x_bf,
    const int* __restrict__ ei, int* __restrict__ hist_mat,
    unsigned* __restrict__ pairs) {
  const int b = blockIdx.x, t = threadIdx.x;
  if (b < 72) {
    prep_one(W1, as1, ad1, wtx1, 4, b * 256 + t);
  } else if (b < 144) {
    prep_one(W2, as2, ad2, wtx2, 1, (b - 72) * 256 + t);
  } else if (b < 144 + CONV_BLKS) {
    const int base = (b - 144) * 2048 + t * 8;
    float4 v0 = *(const float4*)(x + base);
    float4 v1 = *(const float4*)(x + base + 4);
    ushort u[8];
    u[0] = f2bf(v0.x); u[1] = f2bf(v0.y); u[2] = f2bf(v0.z); u[3] = f2bf(v0.w);
    u[4] = f2bf(v1.x); u[5] = f2bf(v1.y); u[6] = f2bf(v1.z); u[7] = f2bf(v1.w);
    *(uint4*)(x_bf + base) = *(const uint4*)u;
  } else {
    __shared__ int hist[NBUCK];
    __shared__ int sflag;
    const int cb = b - 144 - CONV_BLKS;
    if (t < NBUCK) hist[t] = 0;
    const int is64 = detect_inline(ei, &sflag);  // has __syncthreads
    __syncthreads();
    const int e0 = cb * CHUNK;
#pragma unroll
    for (int i = 0; i < CHUNK / 256; ++i) {
      int e = e0 + i * 256 + t;
      if (e < E_TOT) {
        int s, d;
        get_edge(ei, is64, e, s, d);
        pairs[e] = (unsigned)s | ((unsigned)d << 16);
        atomicAdd(&hist[d >> 8], 1);
      }
    }
    __syncthreads();
    if (t < NBUCK) hist_mat[cb * NBUCK + t] = hist[t];
  }
}

// ---------- scatter with self-computed deterministic bases (no global atomics) --
__global__ __launch_bounds__(256) void bucket_scatter(
    const unsigned* __restrict__ pairs, const int* __restrict__ hist_mat,
    unsigned* __restrict__ tmp, int* __restrict__ bstart_g) {
  __shared__ int wtot[4];
  __shared__ int sbase[NBUCK];
  __shared__ int shist[NBUCK];
  const int b = blockIdx.x, t = threadIdx.x, lane = t & 63, wid = t >> 6;
  int tot = 0, pre = 0;
  if (t < NBUCK) {
    for (int bb = 0; bb < NBLK_E; ++bb) {
      int v = hist_mat[bb * NBUCK + t];
      pre += (bb < b) ? v : 0;
      tot += v;
    }
    shist[t] = 0;
  }
  int sc = tot;
#pragma unroll
  for (int m = 1; m < 64; m <<= 1) {
    int o = __shfl_up(sc, m, 64);
    if (lane >= m) sc += o;
  }
  if (lane == 63) wtot[wid] = sc;
  __syncthreads();
  int off = 0;
  for (int w = 0; w < wid; ++w) off += wtot[w];
  const int excl = off + sc - tot;
  if (t < NBUCK) sbase[t] = excl + pre;
  if (b == 0) {
    if (t < NBUCK) bstart_g[t] = excl;
    if (t == 255) bstart_g[NBUCK] = off + sc;
  }
  __syncthreads();
  const int e0 = b * CHUNK;
  unsigned pr_[CHUNK / 256];
  int rk[CHUNK / 256];
#pragma unroll
  for (int i = 0; i < CHUNK / 256; ++i) {
    int e = e0 + i * 256 + t;
    if (e < E_TOT) {
      unsigned pr = pairs[e];
      pr_[i] = pr;
      rk[i] = atomicAdd(&shist[pr >> 24], 1);
    }
  }
#pragma unroll
  for (int i = 0; i < CHUNK / 256; ++i) {
    int e = e0 + i * 256 + t;
    if (e < E_TOT) tmp[sbase[pr_[i] >> 24] + rk[i]] = pr_[i];
  }
}

// ---------- per-bucket counting sort body ----------
__device__ __forceinline__ void bucket_sort_body(int b,
                                                 const unsigned* __restrict__ tmp,
                                                 const int* __restrict__ bstart,
                                                 int* __restrict__ csr_src,
                                                 int* __restrict__ rp,
                                                 int* __restrict__ deg) {
  __shared__ int cnt[256];
  __shared__ int cur[256];
  __shared__ int wtot2[4];
  const int t = threadIdx.x, lane = t & 63, wid = t >> 6;
  const int p0 = bstart[b], p1 = bstart[b + 1];
  cnt[t] = 0;
  __syncthreads();
  for (int j = p0 + t; j < p1; j += 256) {
    unsigned pr = tmp[j];
    atomicAdd(&cnt[(pr >> 16) & 255u], 1);
  }
  __syncthreads();
  int v = cnt[t];
  int sc = v;
#pragma unroll
  for (int m = 1; m < 64; m <<= 1) {
    int o = __shfl_up(sc, m, 64);
    if (lane >= m) sc += o;
  }
  if (lane == 63) wtot2[wid] = sc;
  __syncthreads();
  int off = 0;
  for (int w = 0; w < wid; ++w) off += wtot2[w];
  const int excl = off + sc - v;
  const int node = b * 256 + t;
  if (node < N_NODES) {
    deg[node] = v;
    rp[node] = p0 + excl;
  }
  cur[t] = excl;
  __syncthreads();
  for (int j = p0 + t; j < p1; j += 256) {
    unsigned pr = tmp[j];
    int ld = (int)((pr >> 16) & 255u);
    int r = atomicAdd(&cur[ld], 1);
    csr_src[p0 + r] = (int)(pr & 0xFFFFu);
  }
}

// ---------- MFMA GEMM body (bf16 in) + fused attention-score columns ----------
template <int H>
__device__ __forceinline__ void gemm_att_body(int blk,
                                              const ushort* __restrict__ in_bf,
                                              const ushort* __restrict__ wtx,
                                              ushort* __restrict__ h_bf,
                                              float* __restrict__ a_src,
                                              float* __restrict__ a_dst) {
  const int wid = threadIdx.x >> 6;
  const int lane = threadIdx.x & 63;
  const int tile = blk * 4 + wid;
  if (tile >= N_NODES / 16) return;
  const int row0 = tile * 16;
  const int rA = lane & 15;
  const int g = lane >> 4;

  f32x4 acc[9];
#pragma unroll
  for (int ct = 0; ct < 9; ++ct) acc[ct] = (f32x4){0.f, 0.f, 0.f, 0.f};

#pragma unroll
  for (int ks = 0; ks < 4; ++ks) {
    const int k0 = ks * 32 + g * 8;
    bf16x8 af = *(const bf16x8*)(in_bf + (size_t)(row0 + rA) * DIM + k0);
#pragma unroll
    for (int ct = 0; ct < 9; ++ct) {
      bf16x8 bf = *(const bf16x8*)(wtx + (size_t)(ct * 16 + rA) * 128 + k0);
      acc[ct] = __builtin_amdgcn_mfma_f32_16x16x32_bf16(af, bf, acc[ct], 0, 0, 0);
    }
  }

#pragma unroll
  for (int ct = 0; ct < 8; ++ct) {
#pragma unroll
    for (int r = 0; r < 4; ++r) {
      const int row = row0 + g * 4 + r;
      h_bf[(size_t)row * DIM + ct * 16 + rA] = f2bf(acc[ct][r]);
    }
  }
  if (rA < 2 * H) {
#pragma unroll
    for (int r = 0; r < 4; ++r) {
      const int row = row0 + g * 4 + r;
      if (rA < H)
        a_src[(size_t)row * H + rA] = acc[8][r];
      else
        a_dst[(size_t)row * H + (rA - H)] = acc[8][r];
    }
  }
}

// ---------- fused: gemm_att<4> (blocks 0..GB-1) || bucket_sort (blocks GB..) ----
__global__ __launch_bounds__(256) void gemm4_sort(
    const ushort* __restrict__ x_bf, const ushort* __restrict__ wtx1,
    ushort* __restrict__ h_bf, float* __restrict__ a_src,
    float* __restrict__ a_dst, const unsigned* __restrict__ tmp,
    const int* __restrict__ bstart, int* __restrict__ csr_src,
    int* __restrict__ rp, int* __restrict__ deg) {
  if (blockIdx.x < GB)
    gemm_att_body<4>(blockIdx.x, x_bf, wtx1, h_bf, a_src, a_dst);
  else
    bucket_sort_body(blockIdx.x - GB, tmp, bstart, csr_src, rp, deg);
}

// ---------- standalone gemm_att<1> for layer 2 ----------
__global__ __launch_bounds__(256) void gemm_att1(const ushort* __restrict__ in_bf,
                                                 const ushort* __restrict__ wtx,
                                                 ushort* __restrict__ h_bf,
                                                 float* __restrict__ a_src,
                                                 float* __restrict__ a_dst) {
  gemm_att_body<1>(blockIdx.x, in_bf, wtx, h_bf, a_src, a_dst);
}

// ---------- fused single-pass softmax + gather + bias + relu ----------
// 8 edges/iter: 8 lanes per edge, each lane owns 16 features (2x uint4).
template <int H, bool OBF>
__global__ __launch_bounds__(256) void node_agg(const int* __restrict__ rp,
                                                const int* __restrict__ deg,
                                                const int* __restrict__ csr_src,
                                                const ushort* __restrict__ h_bf,
                                                const float* __restrict__ a_src,
                                                const float* __restrict__ a_dst,
                                                const float* __restrict__ bias,
                                                void* __restrict__ outp) {
  const int wid = threadIdx.x >> 6;
  const int lane = threadIdx.x & 63;
  const int node = blockIdx.x * 4 + wid;
  if (node >= N_NODES) return;
  const int ql = lane >> 3;                   // edge slot 0..7
  const int hl = lane & 7;                    // feature group: 16*hl .. 16*hl+15
  const int head = (H == 4) ? (hl >> 1) : 0;  // 32 features per head
  const float ad = a_dst[(size_t)node * H + head];
  const int beg = rp[node];
  const int dg = deg[node];
  const int* __restrict__ srcs = csr_src + beg;

  float sden = 0.f;
  float acc[16];
#pragma unroll
  for (int k = 0; k < 16; ++k) acc[k] = 0.f;

  int j = 0;
#pragma unroll 2
  for (; j + 8 <= dg; j += 8) {
    int s = srcs[j + ql];
    float v = a_src[(size_t)s * H + head] + ad;
    v = v > 0.f ? v : NEG_SLOPE * v;
    v = fminf(fmaxf(v, -60.f), 80.f);
    float p = __expf(v);
    const uint4* rowp = (const uint4*)(h_bf + (size_t)s * DIM);
    uint4 h0 = rowp[2 * hl];
    uint4 h1 = rowp[2 * hl + 1];
    sden += p;
    acc[0] += p * bf2f_lo(h0.x);  acc[1] += p * bf2f_hi(h0.x);
    acc[2] += p * bf2f_lo(h0.y);  acc[3] += p * bf2f_hi(h0.y);
    acc[4] += p * bf2f_lo(h0.z);  acc[5] += p * bf2f_hi(h0.z);
    acc[6] += p * bf2f_lo(h0.w);  acc[7] += p * bf2f_hi(h0.w);
    acc[8] += p * bf2f_lo(h1.x);  acc[9] += p * bf2f_hi(h1.x);
    acc[10] += p * bf2f_lo(h1.y); acc[11] += p * bf2f_hi(h1.y);
    acc[12] += p * bf2f_lo(h1.z); acc[13] += p * bf2f_hi(h1.z);
    acc[14] += p * bf2f_lo(h1.w); acc[15] += p * bf2f_hi(h1.w);
  }
  if (j < dg) {  // masked tail (1..7 edges)
    int jj = j + ql;
    int s = srcs[jj < dg ? jj : (dg - 1)];
    float v = a_src[(size_t)s * H + head] + ad;
    v = v > 0.f ? v : NEG_SLOPE * v;
    v = fminf(fmaxf(v, -60.f), 80.f);
    float p = (jj < dg) ? __expf(v) : 0.f;
    const uint4* rowp = (const uint4*)(h_bf + (size_t)s * DIM);
    uint4 h0 = rowp[2 * hl];
    uint4 h1 = rowp[2 * hl + 1];
    sden += p;
    acc[0] += p * bf2f_lo(h0.x);  acc[1] += p * bf2f_hi(h0.x);
    acc[2] += p * bf2f_lo(h0.y);  acc[3] += p * bf2f_hi(h0.y);
    acc[4] += p * bf2f_lo(h0.z);  acc[5] += p * bf2f_hi(h0.z);
    acc[6] += p * bf2f_lo(h0.w);  acc[7] += p * bf2f_hi(h0.w);
    acc[8] += p * bf2f_lo(h1.x);  acc[9] += p * bf2f_hi(h1.x);
    acc[10] += p * bf2f_lo(h1.y); acc[11] += p * bf2f_hi(h1.y);
    acc[12] += p * bf2f_lo(h1.z); acc[13] += p * bf2f_hi(h1.z);
    acc[14] += p * bf2f_lo(h1.w); acc[15] += p * bf2f_hi(h1.w);
  }

  // merge 8 edge slots (lanes differing in bits 3..5 share features)
#pragma unroll
  for (int m = 32; m >= 8; m >>= 1) {
    sden += __shfl_xor(sden, m);
#pragma unroll
    for (int k = 0; k < 16; ++k) acc[k] += __shfl_xor(acc[k], m);
  }

  if (lane < 8) {
    const float inv = 1.f / sden;
    float o[16];
#pragma unroll
    for (int q = 0; q < 4; ++q) {
      float4 bv = ((const float4*)bias)[4 * hl + q];
      o[4 * q + 0] = fmaxf(acc[4 * q + 0] * inv + bv.x, 0.f);
      o[4 * q + 1] = fmaxf(acc[4 * q + 1] * inv + bv.y, 0.f);
      o[4 * q + 2] = fmaxf(acc[4 * q + 2] * inv + bv.z, 0.f);
      o[4 * q + 3] = fmaxf(acc[4 * q + 3] * inv + bv.w, 0.f);
    }
    if (OBF) {
      ushort u[16];
#pragma unroll
      for (int k = 0; k < 16; ++k) u[k] = f2bf(o[k]);
      uint4* op = (uint4*)((ushort*)outp + (size_t)node * DIM);
      op[2 * hl] = ((const uint4*)u)[0];
      op[2 * hl + 1] = ((const uint4*)u)[1];
    } else {
      float4* op = (float4*)((float*)outp + (size_t)node * DIM);
#pragma unroll
      for (int q = 0; q < 4; ++q)
        op[4 * hl + q] = make_float4(o[4 * q], o[4 * q + 1], o[4 * q + 2], o[4 * q + 3]);
    }
  }
}

extern "C" void kernel_launch(void* const* d_in, const int* in_sizes, int n_in,
                              void* d_out, int out_size, void* d_ws, size_t ws_size,
                              hipStream_t stream) {
  const float* x   = (const float*)d_in[0];
  const int*   ei  = (const int*)d_in[1];
  const float* W1  = (const float*)d_in[2];
  const float* as1 = (const float*)d_in[3];
  const float* ad1 = (const float*)d_in[4];
  const float* b1  = (const float*)d_in[5];
  const float* W2  = (const float*)d_in[6];
  const float* as2 = (const float*)d_in[7];
  const float* ad2 = (const float*)d_in[8];
  const float* b2  = (const float*)d_in[9];
  float* out = (float*)d_out;

  char* ws = (char*)d_ws;
  const size_t F_H = (size_t)N_NODES * DIM;  // 6.4M elems
  ushort*   h_bf    = (ushort*)ws;                    // 12.8 MB
  ushort*   z_bf    = h_bf + F_H;                     // 12.8 MB
  ushort*   x_bf    = z_bf + F_H;                     // 12.8 MB
  float*    a_src   = (float*)(x_bf + F_H);           // 800 KB
  float*    a_dst   = a_src + 200000;                 // 800 KB
  int*      deg     = (int*)(a_dst + 200000);         // 200 KB
  int*      rp      = deg + N_NODES;                  // 200 KB
  int*      csr_src = rp + N_NODES;                   // 3.4 MB
  unsigned* tmp     = (unsigned*)(csr_src + E_TOT);   // 3.4 MB
  unsigned* pairs   = tmp + E_TOT;                    // 3.4 MB
  int*      hist_mat= (int*)(pairs + E_TOT);          // 163 KB
  int*      bstart  = hist_mat + NBLK_E * NBUCK;      // NBUCK+1
  ushort*   wtx1    = (ushort*)(bstart + NBUCK + 3);  // 36 KB
  ushort*   wtx2    = wtx1 + 144 * 128;               // 36 KB

  const int MEGA = 144 + CONV_BLKS + NBLK_E;  // 3477

  hipLaunchKernelGGL(mega_setup, dim3(MEGA), dim3(256), 0, stream,
                     W1, as1, ad1, wtx1, W2, as2, ad2, wtx2, x, x_bf, ei,
                     hist_mat, pairs);
  hipLaunchKernelGGL(bucket_scatter, dim3(NBLK_E), dim3(256), 0, stream,
                     pairs, hist_mat, tmp, bstart);
  // bucket_sort (196 blocks) runs concurrently with layer-1 GEMM (782 blocks)
  hipLaunchKernelGGL(gemm4_sort, dim3(GB + NBUCK), dim3(256), 0, stream,
                     x_bf, wtx1, h_bf, a_src, a_dst, tmp, bstart, csr_src, rp, deg);
  hipLaunchKernelGGL((node_agg<4, true>), dim3((N_NODES + 3) / 4), dim3(256), 0,
                     stream, rp, deg, csr_src, h_bf, a_src, a_dst, b1, z_bf);

  hipLaunchKernelGGL(gemm_att1, dim3(GB), dim3(256), 0, stream,
                     z_bf, wtx2, h_bf, a_src, a_dst);
  hipLaunchKernelGGL((node_agg<1, false>), dim3((N_NODES + 3) / 4), dim3(256), 0,
                     stream, rp, deg, csr_src, h_bf, a_src, a_dst, b2, out);
}